// Round 5
// baseline (290.727 us; speedup 1.0000x reference)
//
#include <hip/hip_runtime.h>
#include <stdint.h>

typedef __attribute__((ext_vector_type(8))) short short8;
typedef __attribute__((ext_vector_type(4))) float floatx4;
typedef __attribute__((ext_vector_type(16))) float f32x16;
typedef __attribute__((ext_vector_type(4))) unsigned int uint4v;

#define D_MODEL 1024
#define SEQ     2048
#define NHEAD   16
#define HDIM    64
#define BATCH   4
#define NW      (D_MODEL * D_MODEL)

__device__ __forceinline__ unsigned short f2b(float f) {
  unsigned int u = __builtin_bit_cast(unsigned int, f);
  u += 0x7FFFu + ((u >> 16) & 1u);
  return (unsigned short)(u >> 16);
}

__device__ __forceinline__ floatx4 mfma16(short8 a, short8 b, floatx4 c) {
  return __builtin_amdgcn_mfma_f32_16x16x32_bf16(a, b, c, 0, 0, 0);
}
__device__ __forceinline__ f32x16 mfma32(short8 a, short8 b, f32x16 c) {
  return __builtin_amdgcn_mfma_f32_32x32x16_bf16(a, b, c, 0, 0, 0);
}
__device__ __forceinline__ unsigned int cvtpk(float lo, float hi) {
  unsigned int r;
  asm("v_cvt_pk_bf16_f32 %0, %1, %2" : "=v"(r) : "v"(lo), "v"(hi));
  return r;
}
// v_permlane32_swap_b32 a, b: a's lanes 32-63 <-> b's lanes 0-31.
__device__ __forceinline__ void pl32swap(unsigned int &a, unsigned int &b) {
  asm("v_permlane32_swap_b32 %0, %1" : "+v"(a), "+v"(b));
}

#define GLL16(gsrc, ldst)                                                     \
  __builtin_amdgcn_global_load_lds(                                           \
      (const __attribute__((address_space(1))) void*)(gsrc),                  \
      (__attribute__((address_space(3))) void*)(ldst), 16, 0, 0)

// ---------------- f32 -> bf16 conversion ----------------
__global__ void cvt_f32_bf16(const float* __restrict__ in,
                             unsigned short* __restrict__ out, int n) {
  int idx = (blockIdx.x * blockDim.x + threadIdx.x) * 4;
  int stride = gridDim.x * blockDim.x * 4;
  for (int i = idx; i < n; i += stride) {
    float4 v = *reinterpret_cast<const float4*>(in + i);
    ushort4 o;
    o.x = f2b(v.x); o.y = f2b(v.y); o.z = f2b(v.z); o.w = f2b(v.w);
    *reinterpret_cast<ushort4*>(out + i) = o;
  }
}

// Weights + mask prep: blockIdx.y 0..3 -> Wq,Wk,Wv (into Wqkv) / Wo; y==4 -> mask bias.
__global__ void cvt_w(const float* __restrict__ Wq, const float* __restrict__ Wk,
                      const float* __restrict__ Wv, const float* __restrict__ Wo,
                      unsigned short* __restrict__ Wqkv,
                      unsigned short* __restrict__ Wob,
                      const int* __restrict__ mask, float* __restrict__ maskb) {
  const int which = blockIdx.y;
  int idx = (blockIdx.x * blockDim.x + threadIdx.x) * 4;
  int stride = gridDim.x * blockDim.x * 4;
  if (which == 4) {
    for (int i = idx; i < BATCH * SEQ; i += stride) {
      int4 mv = *reinterpret_cast<const int4*>(mask + i);
      float4 o;
      o.x = mv.x ? 0.f : -1e10f;
      o.y = mv.y ? 0.f : -1e10f;
      o.z = mv.z ? 0.f : -1e10f;
      o.w = mv.w ? 0.f : -1e10f;
      *reinterpret_cast<float4*>(maskb + i) = o;
    }
    return;
  }
  const float* s = which == 0 ? Wq : which == 1 ? Wk : which == 2 ? Wv : Wo;
  unsigned short* d = which < 3 ? Wqkv + (size_t)which * NW : Wob;
  for (int i = idx; i < NW; i += stride) {
    float4 v = *reinterpret_cast<const float4*>(s + i);
    ushort4 o;
    o.x = f2b(v.x); o.y = f2b(v.y); o.z = f2b(v.z); o.w = f2b(v.w);
    *reinterpret_cast<ushort4*>(d + i) = o;
  }
}

// Per-(b, 64-key-chunk) "all keys valid" bitmask: flags2[b] bit kt.
__global__ void mask_flags(const int* __restrict__ mask,
                           unsigned int* __restrict__ flags2) {
  const int b = blockIdx.x, l = threadIdx.x;
  int ok = 0;
  if (l < 32) {
    ok = 1;
    for (int i = 0; i < 64; ++i) ok &= mask[b * SEQ + l * 64 + i];
  }
  unsigned long long bal = __ballot(ok);
  if (l == 0) flags2[b] = (unsigned int)bal;
}

// ---------------- GEMM: C[m,n] = sum_k A[m,k]*B[n,k] + bias[n] ----------------
// 128x128 tile, BK=64 (m97 structure), 4 waves, each wave 64x64.
// MODE 1: QKV fused — cols [0,1024) scaled by 0.125*log2e (Q pre-scale);
//   cols [2048,3072) -> transposed bf16 store into VT [b,h][d][s].
// MODE 2: f32 C.
template <int MODE>
__global__ __launch_bounds__(256) void gemm_bt(
    const unsigned short* __restrict__ A, const unsigned short* __restrict__ B,
    const float* __restrict__ bias, void* __restrict__ C,
    unsigned short* __restrict__ VT, int M, int N, int K) {
  __shared__ __align__(16) unsigned short As[128 * 64];
  __shared__ __align__(16) unsigned short Bs[128 * 64];
  const int tid = threadIdx.x;
  const int w = tid >> 6, l = tid & 63, lg = l >> 4, li = l & 15;
  const int m0 = blockIdx.y * 128, n0 = blockIdx.x * 128;
  const int wr = w >> 1, wc = w & 1;

  floatx4 acc[4][4];
#pragma unroll
  for (int m = 0; m < 4; ++m)
#pragma unroll
    for (int n = 0; n < 4; ++n) acc[m][n] = (floatx4){0.f, 0.f, 0.f, 0.f};

  for (int k0 = 0; k0 < K; k0 += 64) {
    __syncthreads();
#pragma unroll
    for (int p = 0; p < 4; ++p) {
      const int c = p * 256 + tid;
      const int row = c >> 3;
      const int co = (c & 7) * 8;
      GLL16(A + (size_t)(m0 + row) * K + k0 + co, As + (p * 256 + w * 64) * 8);
      GLL16(B + (size_t)(n0 + row) * K + k0 + co, Bs + (p * 256 + w * 64) * 8);
    }
    __syncthreads();
#pragma unroll
    for (int kk = 0; kk < 2; ++kk) {
      short8 af[4], bfr[4];
#pragma unroll
      for (int m = 0; m < 4; ++m)
        af[m] = *reinterpret_cast<const short8*>(
            &As[(wr * 64 + m * 16 + li) * 64 + kk * 32 + lg * 8]);
#pragma unroll
      for (int n = 0; n < 4; ++n)
        bfr[n] = *reinterpret_cast<const short8*>(
            &Bs[(wc * 64 + n * 16 + li) * 64 + kk * 32 + lg * 8]);
#pragma unroll
      for (int m = 0; m < 4; ++m)
#pragma unroll
        for (int n = 0; n < 4; ++n) acc[m][n] = mfma16(af[m], bfr[n], acc[m][n]);
    }
  }

#pragma unroll
  for (int m = 0; m < 4; ++m)
#pragma unroll
    for (int n = 0; n < 4; ++n) {
      const int gcol = n0 + wc * 64 + n * 16 + li;
      const float bv = bias[gcol];
      const int grow0 = m0 + wr * 64 + m * 16 + lg * 4;
      if (MODE == 1 && n0 >= 2048) {
        const int vc = gcol - 2048;
        const int hh = vc >> 6, dd = vc & 63;
        const int b = grow0 >> 11, s0 = grow0 & 2047;
        ushort4 pk;
        pk.x = f2b(acc[m][n][0] + bv);
        pk.y = f2b(acc[m][n][1] + bv);
        pk.z = f2b(acc[m][n][2] + bv);
        pk.w = f2b(acc[m][n][3] + bv);
        *reinterpret_cast<ushort4*>(
            &VT[((size_t)((b * NHEAD + hh) * HDIM + dd)) * SEQ + s0]) = pk;
      } else {
        const float scl =
            (MODE == 1 && gcol < 1024) ? 0.18033688011112042f : 1.f;
#pragma unroll
        for (int r = 0; r < 4; ++r) {
          const float val = (acc[m][n][r] + bv) * scl;
          if (MODE == 2)
            reinterpret_cast<float*>(C)[(size_t)(grow0 + r) * N + gcol] = val;
          else
            reinterpret_cast<unsigned short*>(C)[(size_t)(grow0 + r) * N + gcol] =
                f2b(val);
        }
      }
    }
}

// ---------------- Flash attention v4 ----------------
// Swapped-QK^T 32x32, in-register softmax, no max tracking. 4-buffer LDS ring,
// prefetch distance 3, ONE raw barrier per tile with counted vmcnt (T3/T4).
// Decode puts bh in low bits of blockIdx for XCD L2 locality of K/V.
__global__ __launch_bounds__(256) void attn_v4(
    const unsigned short* __restrict__ QKV, const unsigned short* __restrict__ VT,
    const float* __restrict__ maskb, const unsigned int* __restrict__ flags2,
    unsigned short* __restrict__ O) {
  __shared__ __align__(16) unsigned short Kl[4][64 * 64];
  __shared__ __align__(16) unsigned short Vl[4][64 * 64];
  const int tid = threadIdx.x, w = tid >> 6, l = tid & 63;
  const int qi = l & 31, hi = l >> 5;
  const int bid = blockIdx.x;
  const int qblk = bid >> 6, bh = bid & 63, b = bh >> 4, h = bh & 15;
  const int q0 = qblk * 128 + w * 32;

  // Q fragments (B-operand: lane qi = q-col, contraction d = ds*16 + hi*8 + j)
  const unsigned short* qptr = QKV + (size_t)(b * SEQ + q0 + qi) * 3072 + h * 64;
  short8 qf[4];
#pragma unroll
  for (int ds = 0; ds < 4; ++ds)
    qf[ds] = *reinterpret_cast<const short8*>(qptr + ds * 16 + hi * 8);

  // LDS read offsets (ushort units), shared by K and V reads: off[blk][sub]
  int off[2][4];
#pragma unroll
  for (int kb = 0; kb < 2; ++kb)
#pragma unroll
    for (int ds = 0; ds < 4; ++ds)
      off[kb][ds] = (kb * 32 + qi) * 64 + (((ds * 2 + hi) ^ (qi & 7)) * 8);

  // staging pointers (pre-swizzled source; LDS dest linear — rule 21)
  const int srow = tid >> 3;
  const int swz = ((tid & 7) ^ (srow & 7)) * 8;
  const int ldst = (w * 64) * 8;
  const unsigned short* kp0 =
      QKV + (size_t)(b * SEQ) * 3072 + D_MODEL + h * 64 + (size_t)srow * 3072 + swz;
  const unsigned short* kp1 = kp0 + 32 * 3072;
  const unsigned short* vp0 =
      VT + (size_t)((b * NHEAD + h) * HDIM) * SEQ + (size_t)srow * SEQ + swz;
  const unsigned short* vp1 = vp0 + 32 * SEQ;

#define STAGE(BUF)                                                             \
  do {                                                                         \
    GLL16(kp0, &Kl[BUF][ldst]);                                                \
    GLL16(kp1, &Kl[BUF][2048 + ldst]);                                         \
    GLL16(vp0, &Vl[BUF][ldst]);                                                \
    GLL16(vp1, &Vl[BUF][2048 + ldst]);                                         \
    kp0 += 64 * 3072; kp1 += 64 * 3072; vp0 += 64; vp1 += 64;                  \
  } while (0)

  const float* mrow = maskb + b * SEQ;
  const unsigned int fl = flags2[b];
  f32x16 oa[2] = {};
  float l_run = 0.f;  // per-lane partial (own k-half); combined in epilogue

  // TILE core: QK^T -> exp2 -> pack -> PV. No mask (fast path).
#define TILE(BUF)                                                              \
  do {                                                                         \
    f32x16 pa0 = {}, pa1 = {};                                                 \
    __builtin_amdgcn_s_setprio(1);                                             \
    _Pragma("unroll") for (int ds = 0; ds < 4; ++ds) {                         \
      const short8 kf0 =                                                       \
          *reinterpret_cast<const short8*>(&Kl[BUF][off[0][ds]]);              \
      const short8 kf1 =                                                       \
          *reinterpret_cast<const short8*>(&Kl[BUF][off[1][ds]]);              \
      pa0 = mfma32(kf0, qf[ds], pa0);                                          \
      pa1 = mfma32(kf1, qf[ds], pa1);                                          \
    }                                                                          \
    __builtin_amdgcn_s_setprio(0);                                             \
    float r0 = 0.f, r1 = 0.f, r2 = 0.f, r3 = 0.f;                              \
    _Pragma("unroll") for (int r = 0; r < 16; r += 4) {                        \
      float p;                                                                 \
      p = exp2f(pa0[r + 0]); pa0[r + 0] = p; r0 += p;                          \
      p = exp2f(pa0[r + 1]); pa0[r + 1] = p; r1 += p;                          \
      p = exp2f(pa0[r + 2]); pa0[r + 2] = p; r2 += p;                          \
      p = exp2f(pa0[r + 3]); pa0[r + 3] = p; r3 += p;                          \
      p = exp2f(pa1[r + 0]); pa1[r + 0] = p; r0 += p;                          \
      p = exp2f(pa1[r + 1]); pa1[r + 1] = p; r1 += p;                          \
      p = exp2f(pa1[r + 2]); pa1[r + 2] = p; r2 += p;                          \
      p = exp2f(pa1[r + 3]); pa1[r + 3] = p; r3 += p;                          \
    }                                                                          \
    l_run += (r0 + r1) + (r2 + r3);                                            \
    unsigned int c0[8], c1[8];                                                 \
    _Pragma("unroll") for (int u2 = 0; u2 < 8; ++u2) {                         \
      c0[u2] = cvtpk(pa0[2 * u2], pa0[2 * u2 + 1]);                            \
      c1[u2] = cvtpk(pa1[2 * u2], pa1[2 * u2 + 1]);                            \
    }                                                                          \
    pl32swap(c0[0], c0[2]); pl32swap(c0[1], c0[3]);                            \
    pl32swap(c0[4], c0[6]); pl32swap(c0[5], c0[7]);                            \
    pl32swap(c1[0], c1[2]); pl32swap(c1[1], c1[3]);                            \
    pl32swap(c1[4], c1[6]); pl32swap(c1[5], c1[7]);                            \
    __builtin_amdgcn_s_setprio(1);                                             \
    _Pragma("unroll") for (int ks = 0; ks < 4; ++ks) {                         \
      const int kb = ks >> 1, hf = (ks & 1) * 4;                               \
      const short8 pf = __builtin_bit_cast(                                    \
          short8, kb ? (uint4v){c1[hf], c1[hf + 1], c1[hf + 2], c1[hf + 3]}    \
                     : (uint4v){c0[hf], c0[hf + 1], c0[hf + 2], c0[hf + 3]});  \
      const short8 vf0 =                                                       \
          *reinterpret_cast<const short8*>(&Vl[BUF][off[0][ks]]);              \
      const short8 vf1 =                                                       \
          *reinterpret_cast<const short8*>(&Vl[BUF][off[1][ks]]);              \
      oa[0] = mfma32(vf0, pf, oa[0]);                                          \
      oa[1] = mfma32(vf1, pf, oa[1]);                                          \
    }                                                                          \
    __builtin_amdgcn_s_setprio(0);                                             \
  } while (0)

  // Masked variant: adds mask bias between QK^T and exp.
#define TILEM(BUF, KT)                                                         \
  do {                                                                         \
    f32x16 pa0 = {}, pa1 = {};                                                 \
    _Pragma("unroll") for (int ds = 0; ds < 4; ++ds) {                         \
      const short8 kf0 =                                                       \
          *reinterpret_cast<const short8*>(&Kl[BUF][off[0][ds]]);              \
      const short8 kf1 =                                                       \
          *reinterpret_cast<const short8*>(&Kl[BUF][off[1][ds]]);              \
      pa0 = mfma32(kf0, qf[ds], pa0);                                          \
      pa1 = mfma32(kf1, qf[ds], pa1);                                          \
    }                                                                          \
    if (!((fl >> (KT)) & 1)) {                                                 \
      _Pragma("unroll") for (int rq = 0; rq < 4; ++rq) {                       \
        const float4 m0 = *reinterpret_cast<const float4*>(                    \
            mrow + (KT) * 64 + rq * 8 + hi * 4);                               \
        const float4 m1 = *reinterpret_cast<const float4*>(                    \
            mrow + (KT) * 64 + 32 + rq * 8 + hi * 4);                          \
        pa0[rq * 4 + 0] += m0.x; pa0[rq * 4 + 1] += m0.y;                      \
        pa0[rq * 4 + 2] += m0.z; pa0[rq * 4 + 3] += m0.w;                      \
        pa1[rq * 4 + 0] += m1.x; pa1[rq * 4 + 1] += m1.y;                      \
        pa1[rq * 4 + 2] += m1.z; pa1[rq * 4 + 3] += m1.w;                      \
      }                                                                        \
    }                                                                          \
    float r0 = 0.f, r1 = 0.f, r2 = 0.f, r3 = 0.f;                              \
    _Pragma("unroll") for (int r = 0; r < 16; r += 4) {                        \
      float p;                                                                 \
      p = exp2f(pa0[r + 0]); pa0[r + 0] = p; r0 += p;                          \
      p = exp2f(pa0[r + 1]); pa0[r + 1] = p; r1 += p;                          \
      p = exp2f(pa0[r + 2]); pa0[r + 2] = p; r2 += p;                          \
      p = exp2f(pa0[r + 3]); pa0[r + 3] = p; r3 += p;                          \
      p = exp2f(pa1[r + 0]); pa1[r + 0] = p; r0 += p;                          \
      p = exp2f(pa1[r + 1]); pa1[r + 1] = p; r1 += p;                          \
      p = exp2f(pa1[r + 2]); pa1[r + 2] = p; r2 += p;                          \
      p = exp2f(pa1[r + 3]); pa1[r + 3] = p; r3 += p;                          \
    }                                                                          \
    l_run += (r0 + r1) + (r2 + r3);                                            \
    unsigned int c0[8], c1[8];                                                 \
    _Pragma("unroll") for (int u2 = 0; u2 < 8; ++u2) {                         \
      c0[u2] = cvtpk(pa0[2 * u2], pa0[2 * u2 + 1]);                            \
      c1[u2] = cvtpk(pa1[2 * u2], pa1[2 * u2 + 1]);                            \
    }                                                                          \
    pl32swap(c0[0], c0[2]); pl32swap(c0[1], c0[3]);                            \
    pl32swap(c0[4], c0[6]); pl32swap(c0[5], c0[7]);                            \
    pl32swap(c1[0], c1[2]); pl32swap(c1[1], c1[3]);                            \
    pl32swap(c1[4], c1[6]); pl32swap(c1[5], c1[7]);                            \
    _Pragma("unroll") for (int ks = 0; ks < 4; ++ks) {                         \
      const int kb = ks >> 1, hf = (ks & 1) * 4;                               \
      const short8 pf = __builtin_bit_cast(                                    \
          short8, kb ? (uint4v){c1[hf], c1[hf + 1], c1[hf + 2], c1[hf + 3]}    \
                     : (uint4v){c0[hf], c0[hf + 1], c0[hf + 2], c0[hf + 3]});  \
      const short8 vf0 =                                                       \
          *reinterpret_cast<const short8*>(&Vl[BUF][off[0][ks]]);              \
      const short8 vf1 =                                                       \
          *reinterpret_cast<const short8*>(&Vl[BUF][off[1][ks]]);              \
      oa[0] = mfma32(vf0, pf, oa[0]);                                          \
      oa[1] = mfma32(vf1, pf, oa[1]);                                          \
    }                                                                          \
  } while (0)

  // Half-step: counted-vmcnt barrier, then stage tile kt+3, then compute kt.
#define HSF(BUF, SBUF, VMC, DOSTAGE)                                           \
  do {                                                                         \
    asm volatile("s_waitcnt vmcnt(" #VMC ")" ::: "memory");                    \
    __builtin_amdgcn_s_barrier();                                              \
    __builtin_amdgcn_sched_barrier(0);                                         \
    if (DOSTAGE) STAGE(SBUF);                                                  \
    TILE(BUF);                                                                 \
  } while (0)

  STAGE(0); STAGE(1); STAGE(2);  // tiles 0,1,2 in flight (12 loads)

  if (fl == 0xFFFFFFFFu) {
    // Fast path: 1 raw barrier/tile, vmcnt(8) steady state (3 tiles in flight).
#pragma unroll 1
    for (int kt = 0; kt < 28; kt += 4) {
      HSF(0, 3, 8, 1);
      HSF(1, 0, 8, 1);
      HSF(2, 1, 8, 1);
      HSF(3, 2, 8, 1);
    }
    HSF(0, 3, 8, 1);   // kt=28, stages tile 31
    HSF(1, 0, 8, 0);   // kt=29
    HSF(2, 0, 4, 0);   // kt=30
    HSF(3, 0, 0, 0);   // kt=31
  } else {
    // Masked fallback: full-drain barriers (rare; correctness only).
#pragma unroll 1
    for (int kt = 0; kt < 32; kt += 4) {
      __syncthreads();
      if (kt + 3 < 32) STAGE(3);
      TILEM(0, kt + 0);
      __syncthreads();
      if (kt + 4 < 32) STAGE(0);
      TILEM(1, kt + 1);
      __syncthreads();
      if (kt + 5 < 32) STAGE(1);
      TILEM(2, kt + 2);
      __syncthreads();
      if (kt + 6 < 32) STAGE(2);
      TILEM(3, kt + 3);
    }
  }
#undef STAGE
#undef TILE
#undef TILEM
#undef HSF

  // epilogue: combine lane-partial l across k-halves, normalize, repack, store
  l_run += __shfl_xor(l_run, 32);
  const float rinv = 1.f / l_run;
  unsigned int u[2][8];
#pragma unroll
  for (int vb = 0; vb < 2; ++vb) {
#pragma unroll
    for (int uu = 0; uu < 8; ++uu)
      u[vb][uu] = cvtpk(oa[vb][2 * uu] * rinv, oa[vb][2 * uu + 1] * rinv);
    pl32swap(u[vb][0], u[vb][2]);
    pl32swap(u[vb][1], u[vb][3]);
    pl32swap(u[vb][4], u[vb][6]);
    pl32swap(u[vb][5], u[vb][7]);
  }
  unsigned short* optr = O + (size_t)(b * SEQ + q0 + qi) * D_MODEL + h * 64;
#pragma unroll
  for (int cix = 0; cix < 4; ++cix) {
    const int vb = cix >> 1, hf = (cix & 1) * 4;
    *reinterpret_cast<short8*>(optr + cix * 16 + hi * 8) = __builtin_bit_cast(
        short8,
        (uint4v){u[vb][hf], u[vb][hf + 1], u[vb][hf + 2], u[vb][hf + 3]});
  }
}

// ---------------- launch ----------------
extern "C" void kernel_launch(void* const* d_in, const int* in_sizes, int n_in,
                              void* d_out, int out_size, void* d_ws, size_t ws_size,
                              hipStream_t stream) {
  const float* x  = (const float*)d_in[0];
  const int* mask = (const int*)d_in[1];
  const float* Wq = (const float*)d_in[2];
  const float* bq = (const float*)d_in[3];
  const float* Wk = (const float*)d_in[4];
  const float* bk = (const float*)d_in[5];
  const float* Wv = (const float*)d_in[6];
  const float* bv = (const float*)d_in[7];
  const float* Wo = (const float*)d_in[8];
  const float* bo = (const float*)d_in[9];

  char* ws = (char*)d_ws;
  const size_t SZ_X = (size_t)BATCH * SEQ * D_MODEL * 2;  // 16 MB
  unsigned short* xb    = (unsigned short*)(ws);                    // 16 MB @ 0
  unsigned short* Wqkvb = (unsigned short*)(ws + SZ_X);             // 6 MB @ 16M
  unsigned short* Wob   = (unsigned short*)(ws + SZ_X + 6u * 1024 * 1024);  // @ 22M
  unsigned short* QKVb  = (unsigned short*)(ws + 24u * 1024 * 1024);        // 48 MB
  unsigned short* VTb   = (unsigned short*)(ws + 72u * 1024 * 1024);        // 16 MB
  float*          bqkv  = (float*)(ws + 88u * 1024 * 1024);                 // 12 KB
  float*          maskb = (float*)(ws + 88u * 1024 * 1024 + 16384);         // 32 KB
  unsigned int*   flag2 = (unsigned int*)(ws + 88u * 1024 * 1024 + 49152);  // 16 B
  unsigned short* Ob    = xb;  // reuse: xb dead after QKV GEMM

  const int NX = BATCH * SEQ * D_MODEL;  // 8388608
  const int M = BATCH * SEQ;             // 8192

  cvt_f32_bf16<<<2048, 256, 0, stream>>>(x, xb, NX);
  cvt_w<<<dim3(512, 5), 256, 0, stream>>>(Wq, Wk, Wv, Wo, Wqkvb, Wob, mask, maskb);
  mask_flags<<<BATCH, 64, 0, stream>>>(mask, flag2);
  hipMemcpyAsync(bqkv,        bq, D_MODEL * sizeof(float), hipMemcpyDeviceToDevice, stream);
  hipMemcpyAsync(bqkv + 1024, bk, D_MODEL * sizeof(float), hipMemcpyDeviceToDevice, stream);
  hipMemcpyAsync(bqkv + 2048, bv, D_MODEL * sizeof(float), hipMemcpyDeviceToDevice, stream);

  gemm_bt<1><<<dim3(3 * D_MODEL / 128, M / 128), 256, 0, stream>>>(
      xb, Wqkvb, bqkv, QKVb, VTb, M, 3 * D_MODEL, D_MODEL);

  attn_v4<<<BATCH * NHEAD * (SEQ / 128), 256, 0, stream>>>(QKVb, VTb, maskb,
                                                           flag2, Ob);

  gemm_bt<2><<<dim3(D_MODEL / 128, M / 128), 256, 0, stream>>>(
      Ob, Wob, bo, d_out, nullptr, M, D_MODEL, D_MODEL);
}

// Round 6
// 252.280 us; speedup vs baseline: 1.1524x; 1.1524x over previous
//
#include <hip/hip_runtime.h>
#include <stdint.h>

typedef __attribute__((ext_vector_type(8))) short short8;
typedef __attribute__((ext_vector_type(4))) float floatx4;
typedef __attribute__((ext_vector_type(16))) float f32x16;
typedef __attribute__((ext_vector_type(4))) unsigned int uint4v;

#define D_MODEL 1024
#define SEQ     2048
#define NHEAD   16
#define HDIM    64
#define BATCH   4
#define NW      (D_MODEL * D_MODEL)

__device__ __forceinline__ unsigned short f2b(float f) {
  unsigned int u = __builtin_bit_cast(unsigned int, f);
  u += 0x7FFFu + ((u >> 16) & 1u);
  return (unsigned short)(u >> 16);
}

__device__ __forceinline__ floatx4 mfma16(short8 a, short8 b, floatx4 c) {
  return __builtin_amdgcn_mfma_f32_16x16x32_bf16(a, b, c, 0, 0, 0);
}
__device__ __forceinline__ f32x16 mfma32(short8 a, short8 b, f32x16 c) {
  return __builtin_amdgcn_mfma_f32_32x32x16_bf16(a, b, c, 0, 0, 0);
}
__device__ __forceinline__ unsigned int cvtpk(float lo, float hi) {
  unsigned int r;
  asm("v_cvt_pk_bf16_f32 %0, %1, %2" : "=v"(r) : "v"(lo), "v"(hi));
  return r;
}
// v_permlane32_swap_b32 a, b: a's lanes 32-63 <-> b's lanes 0-31.
__device__ __forceinline__ void pl32swap(unsigned int &a, unsigned int &b) {
  asm("v_permlane32_swap_b32 %0, %1" : "+v"(a), "+v"(b));
}

#define GLL16(gsrc, ldst)                                                     \
  __builtin_amdgcn_global_load_lds(                                           \
      (const __attribute__((address_space(1))) void*)(gsrc),                  \
      (__attribute__((address_space(3))) void*)(ldst), 16, 0, 0)

// ---------------- f32 -> bf16 conversion ----------------
__global__ void cvt_f32_bf16(const float* __restrict__ in,
                             unsigned short* __restrict__ out, int n) {
  int idx = (blockIdx.x * blockDim.x + threadIdx.x) * 4;
  int stride = gridDim.x * blockDim.x * 4;
  for (int i = idx; i < n; i += stride) {
    float4 v = *reinterpret_cast<const float4*>(in + i);
    ushort4 o;
    o.x = f2b(v.x); o.y = f2b(v.y); o.z = f2b(v.z); o.w = f2b(v.w);
    *reinterpret_cast<ushort4*>(out + i) = o;
  }
}

// Weights + mask prep: blockIdx.y 0..3 -> Wq,Wk,Wv (into Wqkv) / Wo; y==4 -> mask bias.
__global__ void cvt_w(const float* __restrict__ Wq, const float* __restrict__ Wk,
                      const float* __restrict__ Wv, const float* __restrict__ Wo,
                      unsigned short* __restrict__ Wqkv,
                      unsigned short* __restrict__ Wob,
                      const int* __restrict__ mask, float* __restrict__ maskb) {
  const int which = blockIdx.y;
  int idx = (blockIdx.x * blockDim.x + threadIdx.x) * 4;
  int stride = gridDim.x * blockDim.x * 4;
  if (which == 4) {
    for (int i = idx; i < BATCH * SEQ; i += stride) {
      int4 mv = *reinterpret_cast<const int4*>(mask + i);
      float4 o;
      o.x = mv.x ? 0.f : -1e10f;
      o.y = mv.y ? 0.f : -1e10f;
      o.z = mv.z ? 0.f : -1e10f;
      o.w = mv.w ? 0.f : -1e10f;
      *reinterpret_cast<float4*>(maskb + i) = o;
    }
    return;
  }
  const float* s = which == 0 ? Wq : which == 1 ? Wk : which == 2 ? Wv : Wo;
  unsigned short* d = which < 3 ? Wqkv + (size_t)which * NW : Wob;
  for (int i = idx; i < NW; i += stride) {
    float4 v = *reinterpret_cast<const float4*>(s + i);
    ushort4 o;
    o.x = f2b(v.x); o.y = f2b(v.y); o.z = f2b(v.z); o.w = f2b(v.w);
    *reinterpret_cast<ushort4*>(d + i) = o;
  }
}

// Per-(b, 64-key-chunk) "all keys valid" bitmask: flags2[b] bit kt.
__global__ void mask_flags(const int* __restrict__ mask,
                           unsigned int* __restrict__ flags2) {
  const int b = blockIdx.x, l = threadIdx.x;
  int ok = 0;
  if (l < 32) {
    ok = 1;
    for (int i = 0; i < 64; ++i) ok &= mask[b * SEQ + l * 64 + i];
  }
  unsigned long long bal = __ballot(ok);
  if (l == 0) flags2[b] = (unsigned int)bal;
}

// ---------------- GEMM: C[m,n] = sum_k A[m,k]*B[n,k] + bias[n] ----------------
// 128x128 tile, BK=64 (m97 structure), 4 waves, each wave 64x64.
// T1 XCD-chunked bijective swizzle: consecutive dispatch ids round-robin XCDs;
// remap so each XCD gets a contiguous row-panel chunk (L2 A-reuse).
// MODE 1: QKV fused — cols [0,1024) scaled by 0.125*log2e (Q pre-scale);
//   cols [2048,3072) -> transposed bf16 store into VT [b,h][d][s].
// MODE 2: f32 C.
template <int MODE>
__global__ __launch_bounds__(256) void gemm_bt(
    const unsigned short* __restrict__ A, const unsigned short* __restrict__ B,
    const float* __restrict__ bias, void* __restrict__ C,
    unsigned short* __restrict__ VT, int M, int N, int K) {
  __shared__ __align__(16) unsigned short As[128 * 64];
  __shared__ __align__(16) unsigned short Bs[128 * 64];
  const int tid = threadIdx.x;
  const int w = tid >> 6, l = tid & 63, lg = l >> 4, li = l & 15;
  // XCD swizzle (nwg divisible by 8 for both modes; GX known at compile time)
  const int GX = (MODE == 1) ? 24 : 8;      // N/128
  const int NWG = GX * 64;                   // M/128 = 64
  int id = blockIdx.y * GX + blockIdx.x;
  id = (id & 7) * (NWG >> 3) + (id >> 3);
  const int m0 = (id / GX) * 128, n0 = (id % GX) * 128;
  const int wr = w >> 1, wc = w & 1;

  floatx4 acc[4][4];
#pragma unroll
  for (int m = 0; m < 4; ++m)
#pragma unroll
    for (int n = 0; n < 4; ++n) acc[m][n] = (floatx4){0.f, 0.f, 0.f, 0.f};

  for (int k0 = 0; k0 < K; k0 += 64) {
    __syncthreads();
#pragma unroll
    for (int p = 0; p < 4; ++p) {
      const int c = p * 256 + tid;
      const int row = c >> 3;
      const int co = (c & 7) * 8;
      GLL16(A + (size_t)(m0 + row) * K + k0 + co, As + (p * 256 + w * 64) * 8);
      GLL16(B + (size_t)(n0 + row) * K + k0 + co, Bs + (p * 256 + w * 64) * 8);
    }
    __syncthreads();
#pragma unroll
    for (int kk = 0; kk < 2; ++kk) {
      short8 af[4], bfr[4];
#pragma unroll
      for (int m = 0; m < 4; ++m)
        af[m] = *reinterpret_cast<const short8*>(
            &As[(wr * 64 + m * 16 + li) * 64 + kk * 32 + lg * 8]);
#pragma unroll
      for (int n = 0; n < 4; ++n)
        bfr[n] = *reinterpret_cast<const short8*>(
            &Bs[(wc * 64 + n * 16 + li) * 64 + kk * 32 + lg * 8]);
#pragma unroll
      for (int m = 0; m < 4; ++m)
#pragma unroll
        for (int n = 0; n < 4; ++n) acc[m][n] = mfma16(af[m], bfr[n], acc[m][n]);
    }
  }

#pragma unroll
  for (int m = 0; m < 4; ++m)
#pragma unroll
    for (int n = 0; n < 4; ++n) {
      const int gcol = n0 + wc * 64 + n * 16 + li;
      const float bv = bias[gcol];
      const int grow0 = m0 + wr * 64 + m * 16 + lg * 4;
      if (MODE == 1 && n0 >= 2048) {
        const int vc = gcol - 2048;
        const int hh = vc >> 6, dd = vc & 63;
        const int b = grow0 >> 11, s0 = grow0 & 2047;
        ushort4 pk;
        pk.x = f2b(acc[m][n][0] + bv);
        pk.y = f2b(acc[m][n][1] + bv);
        pk.z = f2b(acc[m][n][2] + bv);
        pk.w = f2b(acc[m][n][3] + bv);
        *reinterpret_cast<ushort4*>(
            &VT[((size_t)((b * NHEAD + hh) * HDIM + dd)) * SEQ + s0]) = pk;
      } else {
        const float scl =
            (MODE == 1 && gcol < 1024) ? 0.18033688011112042f : 1.f;
#pragma unroll
        for (int r = 0; r < 4; ++r) {
          const float val = (acc[m][n][r] + bv) * scl;
          if (MODE == 2)
            reinterpret_cast<float*>(C)[(size_t)(grow0 + r) * N + gcol] = val;
          else
            reinterpret_cast<unsigned short*>(C)[(size_t)(grow0 + r) * N + gcol] =
                f2b(val);
        }
      }
    }
}

// ---------------- Flash attention v5 ----------------
// v3 structure (2-buffer, 32KB LDS, 1 barrier/tile, stage-before-compute)
// + XCD decode (bh in low bits; confirmed FETCH halving)
// + deferred l-combine (per-lane partial, one shuffle in epilogue).
__global__ __launch_bounds__(256) void attn_v5(
    const unsigned short* __restrict__ QKV, const unsigned short* __restrict__ VT,
    const float* __restrict__ maskb, const unsigned int* __restrict__ flags2,
    unsigned short* __restrict__ O) {
  __shared__ __align__(16) unsigned short Kl[2][64 * 64];
  __shared__ __align__(16) unsigned short Vl[2][64 * 64];
  const int tid = threadIdx.x, w = tid >> 6, l = tid & 63;
  const int qi = l & 31, hi = l >> 5;
  const int bid = blockIdx.x;
  const int qblk = bid >> 6, bh = bid & 63, b = bh >> 4, h = bh & 15;
  const int q0 = qblk * 128 + w * 32;

  // Q fragments (B-operand: lane qi = q-col, contraction d = ds*16 + hi*8 + j)
  const unsigned short* qptr = QKV + (size_t)(b * SEQ + q0 + qi) * 3072 + h * 64;
  short8 qf[4];
#pragma unroll
  for (int ds = 0; ds < 4; ++ds)
    qf[ds] = *reinterpret_cast<const short8*>(qptr + ds * 16 + hi * 8);

  // LDS read offsets (ushort units), shared by K and V reads: off[blk][sub]
  int off[2][4];
#pragma unroll
  for (int kb = 0; kb < 2; ++kb)
#pragma unroll
    for (int ds = 0; ds < 4; ++ds)
      off[kb][ds] = (kb * 32 + qi) * 64 + (((ds * 2 + hi) ^ (qi & 7)) * 8);

  // staging pointers (pre-swizzled source; LDS dest linear — rule 21)
  const int srow = tid >> 3;
  const int swz = ((tid & 7) ^ (srow & 7)) * 8;
  const int ldst = (w * 64) * 8;
  const unsigned short* kp0 =
      QKV + (size_t)(b * SEQ) * 3072 + D_MODEL + h * 64 + (size_t)srow * 3072 + swz;
  const unsigned short* kp1 = kp0 + 32 * 3072;
  const unsigned short* vp0 =
      VT + (size_t)((b * NHEAD + h) * HDIM) * SEQ + (size_t)srow * SEQ + swz;
  const unsigned short* vp1 = vp0 + 32 * SEQ;

#define STAGE(BUF)                                                             \
  do {                                                                         \
    GLL16(kp0, &Kl[BUF][ldst]);                                                \
    GLL16(kp1, &Kl[BUF][2048 + ldst]);                                         \
    GLL16(vp0, &Vl[BUF][ldst]);                                                \
    GLL16(vp1, &Vl[BUF][2048 + ldst]);                                         \
    kp0 += 64 * 3072; kp1 += 64 * 3072; vp0 += 64; vp1 += 64;                  \
  } while (0)

  const float* mrow = maskb + b * SEQ;
  const unsigned int fl = flags2[b];
  f32x16 oa[2] = {};
  float l_run = 0.f;  // per-lane partial (own k-half); combined in epilogue

#define TILE(BUF, KT)                                                          \
  do {                                                                         \
    f32x16 pa0 = {}, pa1 = {};                                                 \
    __builtin_amdgcn_s_setprio(1);                                             \
    _Pragma("unroll") for (int ds = 0; ds < 4; ++ds) {                         \
      const short8 kf0 =                                                       \
          *reinterpret_cast<const short8*>(&Kl[BUF][off[0][ds]]);              \
      const short8 kf1 =                                                       \
          *reinterpret_cast<const short8*>(&Kl[BUF][off[1][ds]]);              \
      pa0 = mfma32(kf0, qf[ds], pa0);                                          \
      pa1 = mfma32(kf1, qf[ds], pa1);                                          \
    }                                                                          \
    __builtin_amdgcn_s_setprio(0);                                             \
    if (!((fl >> (KT)) & 1)) { /* slow path: some keys masked */               \
      _Pragma("unroll") for (int rq = 0; rq < 4; ++rq) {                       \
        const float4 m0 = *reinterpret_cast<const float4*>(                    \
            mrow + (KT) * 64 + rq * 8 + hi * 4);                               \
        const float4 m1 = *reinterpret_cast<const float4*>(                    \
            mrow + (KT) * 64 + 32 + rq * 8 + hi * 4);                          \
        pa0[rq * 4 + 0] += m0.x; pa0[rq * 4 + 1] += m0.y;                      \
        pa0[rq * 4 + 2] += m0.z; pa0[rq * 4 + 3] += m0.w;                      \
        pa1[rq * 4 + 0] += m1.x; pa1[rq * 4 + 1] += m1.y;                      \
        pa1[rq * 4 + 2] += m1.z; pa1[rq * 4 + 3] += m1.w;                      \
      }                                                                        \
    }                                                                          \
    float r0 = 0.f, r1 = 0.f, r2 = 0.f, r3 = 0.f;                              \
    _Pragma("unroll") for (int r = 0; r < 16; r += 4) {                        \
      float p;                                                                 \
      p = exp2f(pa0[r + 0]); pa0[r + 0] = p; r0 += p;                          \
      p = exp2f(pa0[r + 1]); pa0[r + 1] = p; r1 += p;                          \
      p = exp2f(pa0[r + 2]); pa0[r + 2] = p; r2 += p;                          \
      p = exp2f(pa0[r + 3]); pa0[r + 3] = p; r3 += p;                          \
      p = exp2f(pa1[r + 0]); pa1[r + 0] = p; r0 += p;                          \
      p = exp2f(pa1[r + 1]); pa1[r + 1] = p; r1 += p;                          \
      p = exp2f(pa1[r + 2]); pa1[r + 2] = p; r2 += p;                          \
      p = exp2f(pa1[r + 3]); pa1[r + 3] = p; r3 += p;                          \
    }                                                                          \
    l_run += (r0 + r1) + (r2 + r3);                                            \
    unsigned int c0[8], c1[8];                                                 \
    _Pragma("unroll") for (int u2 = 0; u2 < 8; ++u2) {                         \
      c0[u2] = cvtpk(pa0[2 * u2], pa0[2 * u2 + 1]);                            \
      c1[u2] = cvtpk(pa1[2 * u2], pa1[2 * u2 + 1]);                            \
    }                                                                          \
    pl32swap(c0[0], c0[2]); pl32swap(c0[1], c0[3]);                            \
    pl32swap(c0[4], c0[6]); pl32swap(c0[5], c0[7]);                            \
    pl32swap(c1[0], c1[2]); pl32swap(c1[1], c1[3]);                            \
    pl32swap(c1[4], c1[6]); pl32swap(c1[5], c1[7]);                            \
    __builtin_amdgcn_s_setprio(1);                                             \
    _Pragma("unroll") for (int ks = 0; ks < 4; ++ks) {                         \
      const int kb = ks >> 1, hf = (ks & 1) * 4;                               \
      const short8 pf = __builtin_bit_cast(                                    \
          short8, kb ? (uint4v){c1[hf], c1[hf + 1], c1[hf + 2], c1[hf + 3]}    \
                     : (uint4v){c0[hf], c0[hf + 1], c0[hf + 2], c0[hf + 3]});  \
      const short8 vf0 =                                                       \
          *reinterpret_cast<const short8*>(&Vl[BUF][off[0][ks]]);              \
      const short8 vf1 =                                                       \
          *reinterpret_cast<const short8*>(&Vl[BUF][off[1][ks]]);              \
      oa[0] = mfma32(vf0, pf, oa[0]);                                          \
      oa[1] = mfma32(vf1, pf, oa[1]);                                          \
    }                                                                          \
    __builtin_amdgcn_s_setprio(0);                                             \
  } while (0)

  STAGE(0);  // tile 0
  __syncthreads();
#pragma unroll 1
  for (int kt = 0; kt < 32; kt += 2) {
    STAGE(1);  // tile kt+1 in flight while computing kt
    TILE(0, kt);
    __syncthreads();
    if (kt + 2 < 32) STAGE(0);  // tile kt+2
    TILE(1, kt + 1);
    __syncthreads();
  }
#undef STAGE
#undef TILE

  // epilogue: combine lane-partial l across k-halves, normalize, repack, store
  l_run += __shfl_xor(l_run, 32);
  const float rinv = 1.f / l_run;
  unsigned int u[2][8];
#pragma unroll
  for (int vb = 0; vb < 2; ++vb) {
#pragma unroll
    for (int uu = 0; uu < 8; ++uu)
      u[vb][uu] = cvtpk(oa[vb][2 * uu] * rinv, oa[vb][2 * uu + 1] * rinv);
    pl32swap(u[vb][0], u[vb][2]);
    pl32swap(u[vb][1], u[vb][3]);
    pl32swap(u[vb][4], u[vb][6]);
    pl32swap(u[vb][5], u[vb][7]);
  }
  unsigned short* optr = O + (size_t)(b * SEQ + q0 + qi) * D_MODEL + h * 64;
#pragma unroll
  for (int cix = 0; cix < 4; ++cix) {
    const int vb = cix >> 1, hf = (cix & 1) * 4;
    *reinterpret_cast<short8*>(optr + cix * 16 + hi * 8) = __builtin_bit_cast(
        short8,
        (uint4v){u[vb][hf], u[vb][hf + 1], u[vb][hf + 2], u[vb][hf + 3]});
  }
}

// ---------------- launch ----------------
extern "C" void kernel_launch(void* const* d_in, const int* in_sizes, int n_in,
                              void* d_out, int out_size, void* d_ws, size_t ws_size,
                              hipStream_t stream) {
  const float* x  = (const float*)d_in[0];
  const int* mask = (const int*)d_in[1];
  const float* Wq = (const float*)d_in[2];
  const float* bq = (const float*)d_in[3];
  const float* Wk = (const float*)d_in[4];
  const float* bk = (const float*)d_in[5];
  const float* Wv = (const float*)d_in[6];
  const float* bv = (const float*)d_in[7];
  const float* Wo = (const float*)d_in[8];
  const float* bo = (const float*)d_in[9];

  char* ws = (char*)d_ws;
  const size_t SZ_X = (size_t)BATCH * SEQ * D_MODEL * 2;  // 16 MB
  unsigned short* xb    = (unsigned short*)(ws);                    // 16 MB @ 0
  unsigned short* Wqkvb = (unsigned short*)(ws + SZ_X);             // 6 MB @ 16M
  unsigned short* Wob   = (unsigned short*)(ws + SZ_X + 6u * 1024 * 1024);  // @ 22M
  unsigned short* QKVb  = (unsigned short*)(ws + 24u * 1024 * 1024);        // 48 MB
  unsigned short* VTb   = (unsigned short*)(ws + 72u * 1024 * 1024);        // 16 MB
  float*          bqkv  = (float*)(ws + 88u * 1024 * 1024);                 // 12 KB
  float*          maskb = (float*)(ws + 88u * 1024 * 1024 + 16384);         // 32 KB
  unsigned int*   flag2 = (unsigned int*)(ws + 88u * 1024 * 1024 + 49152);  // 16 B
  unsigned short* Ob    = xb;  // reuse: xb dead after QKV GEMM

  const int NX = BATCH * SEQ * D_MODEL;  // 8388608
  const int M = BATCH * SEQ;             // 8192

  cvt_f32_bf16<<<2048, 256, 0, stream>>>(x, xb, NX);
  cvt_w<<<dim3(512, 5), 256, 0, stream>>>(Wq, Wk, Wv, Wo, Wqkvb, Wob, mask, maskb);
  mask_flags<<<BATCH, 64, 0, stream>>>(mask, flag2);
  hipMemcpyAsync(bqkv,        bq, D_MODEL * sizeof(float), hipMemcpyDeviceToDevice, stream);
  hipMemcpyAsync(bqkv + 1024, bk, D_MODEL * sizeof(float), hipMemcpyDeviceToDevice, stream);
  hipMemcpyAsync(bqkv + 2048, bv, D_MODEL * sizeof(float), hipMemcpyDeviceToDevice, stream);

  gemm_bt<1><<<dim3(3 * D_MODEL / 128, M / 128), 256, 0, stream>>>(
      xb, Wqkvb, bqkv, QKVb, VTb, M, 3 * D_MODEL, D_MODEL);

  attn_v5<<<BATCH * NHEAD * (SEQ / 128), 256, 0, stream>>>(QKVb, VTb, maskb,
                                                           flag2, Ob);

  gemm_bt<2><<<dim3(D_MODEL / 128, M / 128), 256, 0, stream>>>(
      Ob, Wob, bo, d_out, nullptr, M, D_MODEL, D_MODEL);
}

// Round 7
// 244.951 us; speedup vs baseline: 1.1869x; 1.0299x over previous
//
#include <hip/hip_runtime.h>
#include <stdint.h>

typedef __attribute__((ext_vector_type(8))) short short8;
typedef __attribute__((ext_vector_type(4))) float floatx4;
typedef __attribute__((ext_vector_type(16))) float f32x16;
typedef __attribute__((ext_vector_type(4))) unsigned int uint4v;

#define D_MODEL 1024
#define SEQ     2048
#define NHEAD   16
#define HDIM    64
#define BATCH   4
#define NW      (D_MODEL * D_MODEL)

__device__ __forceinline__ unsigned short f2b(float f) {
  unsigned int u = __builtin_bit_cast(unsigned int, f);
  u += 0x7FFFu + ((u >> 16) & 1u);
  return (unsigned short)(u >> 16);
}

__device__ __forceinline__ floatx4 mfma16(short8 a, short8 b, floatx4 c) {
  return __builtin_amdgcn_mfma_f32_16x16x32_bf16(a, b, c, 0, 0, 0);
}
__device__ __forceinline__ f32x16 mfma32(short8 a, short8 b, f32x16 c) {
  return __builtin_amdgcn_mfma_f32_32x32x16_bf16(a, b, c, 0, 0, 0);
}
__device__ __forceinline__ unsigned int cvtpk(float lo, float hi) {
  unsigned int r;
  asm("v_cvt_pk_bf16_f32 %0, %1, %2" : "=v"(r) : "v"(lo), "v"(hi));
  return r;
}
// v_permlane32_swap_b32 a, b: a's lanes 32-63 <-> b's lanes 0-31.
__device__ __forceinline__ void pl32swap(unsigned int &a, unsigned int &b) {
  asm("v_permlane32_swap_b32 %0, %1" : "+v"(a), "+v"(b));
}

#define GLL16(gsrc, ldst)                                                     \
  __builtin_amdgcn_global_load_lds(                                           \
      (const __attribute__((address_space(1))) void*)(gsrc),                  \
      (__attribute__((address_space(3))) void*)(ldst), 16, 0, 0)

// ---------------- f32 -> bf16 conversion ----------------
__global__ void cvt_f32_bf16(const float* __restrict__ in,
                             unsigned short* __restrict__ out, int n) {
  int idx = (blockIdx.x * blockDim.x + threadIdx.x) * 4;
  int stride = gridDim.x * blockDim.x * 4;
  for (int i = idx; i < n; i += stride) {
    float4 v = *reinterpret_cast<const float4*>(in + i);
    ushort4 o;
    o.x = f2b(v.x); o.y = f2b(v.y); o.z = f2b(v.z); o.w = f2b(v.w);
    *reinterpret_cast<ushort4*>(out + i) = o;
  }
}

// Weights + mask prep: blockIdx.y 0..3 -> Wq,Wk,Wv (into Wqkv) / Wo; y==4 -> mask bias.
__global__ void cvt_w(const float* __restrict__ Wq, const float* __restrict__ Wk,
                      const float* __restrict__ Wv, const float* __restrict__ Wo,
                      unsigned short* __restrict__ Wqkv,
                      unsigned short* __restrict__ Wob,
                      const int* __restrict__ mask, float* __restrict__ maskb) {
  const int which = blockIdx.y;
  int idx = (blockIdx.x * blockDim.x + threadIdx.x) * 4;
  int stride = gridDim.x * blockDim.x * 4;
  if (which == 4) {
    for (int i = idx; i < BATCH * SEQ; i += stride) {
      int4 mv = *reinterpret_cast<const int4*>(mask + i);
      float4 o;
      o.x = mv.x ? 0.f : -1e10f;
      o.y = mv.y ? 0.f : -1e10f;
      o.z = mv.z ? 0.f : -1e10f;
      o.w = mv.w ? 0.f : -1e10f;
      *reinterpret_cast<float4*>(maskb + i) = o;
    }
    return;
  }
  const float* s = which == 0 ? Wq : which == 1 ? Wk : which == 2 ? Wv : Wo;
  unsigned short* d = which < 3 ? Wqkv + (size_t)which * NW : Wob;
  for (int i = idx; i < NW; i += stride) {
    float4 v = *reinterpret_cast<const float4*>(s + i);
    ushort4 o;
    o.x = f2b(v.x); o.y = f2b(v.y); o.z = f2b(v.z); o.w = f2b(v.w);
    *reinterpret_cast<ushort4*>(d + i) = o;
  }
}

// Per-(b, 64-key-chunk) "all keys valid" bitmask + bias concat (fused).
__global__ void mask_flags(const int* __restrict__ mask,
                           unsigned int* __restrict__ flags2,
                           const float* __restrict__ bq,
                           const float* __restrict__ bk,
                           const float* __restrict__ bv,
                           float* __restrict__ bqkv) {
  const int b = blockIdx.x, tid = threadIdx.x;
  if (tid < 64) {
    int ok = 0;
    if (tid < 32) {
      ok = 1;
      for (int i = 0; i < 64; ++i) ok &= mask[b * SEQ + tid * 64 + i];
    }
    unsigned long long bal = __ballot(ok);
    if (tid == 0) flags2[b] = (unsigned int)bal;
  }
  const int i = blockIdx.x * 256 + tid;  // 0..1023
  bqkv[i] = bq[i];
  bqkv[1024 + i] = bk[i];
  bqkv[2048 + i] = bv[i];
}

// ---------------- GEMM: C[m,n] = sum_k A[m,k]*B[n,k] + bias[n] ----------------
// 128x128 tile, BK=64 (m97 structure), 4 waves, each wave 64x64.
// T1 XCD-chunked bijective swizzle for L2 A-reuse.
// MODE 1: QKV fused — cols [0,1024) scaled by 0.125*log2e (Q pre-scale);
//   cols [2048,3072) -> transposed bf16 store into VT [b,h][d][s].
// MODE 2: f32 C.
template <int MODE>
__global__ __launch_bounds__(256) void gemm_bt(
    const unsigned short* __restrict__ A, const unsigned short* __restrict__ B,
    const float* __restrict__ bias, void* __restrict__ C,
    unsigned short* __restrict__ VT, int M, int N, int K) {
  __shared__ __align__(16) unsigned short As[128 * 64];
  __shared__ __align__(16) unsigned short Bs[128 * 64];
  const int tid = threadIdx.x;
  const int w = tid >> 6, l = tid & 63, lg = l >> 4, li = l & 15;
  const int GX = (MODE == 1) ? 24 : 8;      // N/128
  const int NWG = GX * 64;                   // M/128 = 64
  int id = blockIdx.y * GX + blockIdx.x;
  id = (id & 7) * (NWG >> 3) + (id >> 3);
  const int m0 = (id / GX) * 128, n0 = (id % GX) * 128;
  const int wr = w >> 1, wc = w & 1;

  floatx4 acc[4][4];
#pragma unroll
  for (int m = 0; m < 4; ++m)
#pragma unroll
    for (int n = 0; n < 4; ++n) acc[m][n] = (floatx4){0.f, 0.f, 0.f, 0.f};

  for (int k0 = 0; k0 < K; k0 += 64) {
    __syncthreads();
#pragma unroll
    for (int p = 0; p < 4; ++p) {
      const int c = p * 256 + tid;
      const int row = c >> 3;
      const int co = (c & 7) * 8;
      GLL16(A + (size_t)(m0 + row) * K + k0 + co, As + (p * 256 + w * 64) * 8);
      GLL16(B + (size_t)(n0 + row) * K + k0 + co, Bs + (p * 256 + w * 64) * 8);
    }
    __syncthreads();
#pragma unroll
    for (int kk = 0; kk < 2; ++kk) {
      short8 af[4], bfr[4];
#pragma unroll
      for (int m = 0; m < 4; ++m)
        af[m] = *reinterpret_cast<const short8*>(
            &As[(wr * 64 + m * 16 + li) * 64 + kk * 32 + lg * 8]);
#pragma unroll
      for (int n = 0; n < 4; ++n)
        bfr[n] = *reinterpret_cast<const short8*>(
            &Bs[(wc * 64 + n * 16 + li) * 64 + kk * 32 + lg * 8]);
#pragma unroll
      for (int m = 0; m < 4; ++m)
#pragma unroll
        for (int n = 0; n < 4; ++n) acc[m][n] = mfma16(af[m], bfr[n], acc[m][n]);
    }
  }

#pragma unroll
  for (int m = 0; m < 4; ++m)
#pragma unroll
    for (int n = 0; n < 4; ++n) {
      const int gcol = n0 + wc * 64 + n * 16 + li;
      const float bv = bias[gcol];
      const int grow0 = m0 + wr * 64 + m * 16 + lg * 4;
      if (MODE == 1 && n0 >= 2048) {
        const int vc = gcol - 2048;
        const int hh = vc >> 6, dd = vc & 63;
        const int b = grow0 >> 11, s0 = grow0 & 2047;
        ushort4 pk;
        pk.x = f2b(acc[m][n][0] + bv);
        pk.y = f2b(acc[m][n][1] + bv);
        pk.z = f2b(acc[m][n][2] + bv);
        pk.w = f2b(acc[m][n][3] + bv);
        *reinterpret_cast<ushort4*>(
            &VT[((size_t)((b * NHEAD + hh) * HDIM + dd)) * SEQ + s0]) = pk;
      } else {
        const float scl =
            (MODE == 1 && gcol < 1024) ? 0.18033688011112042f : 1.f;
#pragma unroll
        for (int r = 0; r < 4; ++r) {
          const float val = (acc[m][n][r] + bv) * scl;
          if (MODE == 2)
            reinterpret_cast<float*>(C)[(size_t)(grow0 + r) * N + gcol] = val;
          else
            reinterpret_cast<unsigned short*>(C)[(size_t)(grow0 + r) * N + gcol] =
                f2b(val);
        }
      }
    }
}

// ---------------- Flash attention v6: 8 waves x 32 q (QBLK=256) ----------------
// Same per-wave math as v5; 512 threads/block raises resident waves/SIMD to 4
// (2 blocks/CU x 8 waves) for latency hiding. 1 barrier/tile, 2-buffer LDS.
__global__ __launch_bounds__(512) void attn_v6(
    const unsigned short* __restrict__ QKV, const unsigned short* __restrict__ VT,
    const float* __restrict__ maskb, const unsigned int* __restrict__ flags2,
    unsigned short* __restrict__ O) {
  __shared__ __align__(16) unsigned short Kl[2][64 * 64];
  __shared__ __align__(16) unsigned short Vl[2][64 * 64];
  const int tid = threadIdx.x, w = tid >> 6, l = tid & 63;
  const int qi = l & 31, hi = l >> 5;
  const int bid = blockIdx.x;
  const int qblk = bid >> 6, bh = bid & 63, b = bh >> 4, h = bh & 15;
  const int q0 = qblk * 256 + w * 32;

  // Q fragments (B-operand: lane qi = q-col, contraction d = ds*16 + hi*8 + j)
  const unsigned short* qptr = QKV + (size_t)(b * SEQ + q0 + qi) * 3072 + h * 64;
  short8 qf[4];
#pragma unroll
  for (int ds = 0; ds < 4; ++ds)
    qf[ds] = *reinterpret_cast<const short8*>(qptr + ds * 16 + hi * 8);

  // LDS read offsets (ushort units), shared by K and V reads: off[blk][sub]
  int off[2][4];
#pragma unroll
  for (int kb = 0; kb < 2; ++kb)
#pragma unroll
    for (int ds = 0; ds < 4; ++ds)
      off[kb][ds] = (kb * 32 + qi) * 64 + (((ds * 2 + hi) ^ (qi & 7)) * 8);

  // staging: 512 threads cover 64x64 tile: 1 chunk K + 1 chunk V per thread.
  // srow = tid>>3 (0..63), slot = tid&7; source pre-swizzled (rule 21).
  const int srow = tid >> 3;
  const int swz = ((tid & 7) ^ (srow & 7)) * 8;
  const int ldst = w * 512;  // wave-uniform LDS base (ushort units)
  const unsigned short* kp0 =
      QKV + (size_t)(b * SEQ) * 3072 + D_MODEL + h * 64 + (size_t)srow * 3072 + swz;
  const unsigned short* vp0 =
      VT + (size_t)((b * NHEAD + h) * HDIM) * SEQ + (size_t)srow * SEQ + swz;

#define STAGE(BUF)                                                             \
  do {                                                                         \
    GLL16(kp0, &Kl[BUF][ldst]);                                                \
    GLL16(vp0, &Vl[BUF][ldst]);                                                \
    kp0 += 64 * 3072; vp0 += 64;                                               \
  } while (0)

  const float* mrow = maskb + b * SEQ;
  const unsigned int fl = flags2[b];
  f32x16 oa[2] = {};
  float l_run = 0.f;  // per-lane partial (own k-half); combined in epilogue

#define TILE(BUF, KT)                                                          \
  do {                                                                         \
    f32x16 pa0 = {}, pa1 = {};                                                 \
    __builtin_amdgcn_s_setprio(1);                                             \
    _Pragma("unroll") for (int ds = 0; ds < 4; ++ds) {                         \
      const short8 kf0 =                                                       \
          *reinterpret_cast<const short8*>(&Kl[BUF][off[0][ds]]);              \
      const short8 kf1 =                                                       \
          *reinterpret_cast<const short8*>(&Kl[BUF][off[1][ds]]);              \
      pa0 = mfma32(kf0, qf[ds], pa0);                                          \
      pa1 = mfma32(kf1, qf[ds], pa1);                                          \
    }                                                                          \
    __builtin_amdgcn_s_setprio(0);                                             \
    if (!((fl >> (KT)) & 1)) { /* slow path: some keys masked */               \
      _Pragma("unroll") for (int rq = 0; rq < 4; ++rq) {                       \
        const float4 m0 = *reinterpret_cast<const float4*>(                    \
            mrow + (KT) * 64 + rq * 8 + hi * 4);                               \
        const float4 m1 = *reinterpret_cast<const float4*>(                    \
            mrow + (KT) * 64 + 32 + rq * 8 + hi * 4);                          \
        pa0[rq * 4 + 0] += m0.x; pa0[rq * 4 + 1] += m0.y;                      \
        pa0[rq * 4 + 2] += m0.z; pa0[rq * 4 + 3] += m0.w;                      \
        pa1[rq * 4 + 0] += m1.x; pa1[rq * 4 + 1] += m1.y;                      \
        pa1[rq * 4 + 2] += m1.z; pa1[rq * 4 + 3] += m1.w;                      \
      }                                                                        \
    }                                                                          \
    float r0 = 0.f, r1 = 0.f, r2 = 0.f, r3 = 0.f;                              \
    _Pragma("unroll") for (int r = 0; r < 16; r += 4) {                        \
      float p;                                                                 \
      p = exp2f(pa0[r + 0]); pa0[r + 0] = p; r0 += p;                          \
      p = exp2f(pa0[r + 1]); pa0[r + 1] = p; r1 += p;                          \
      p = exp2f(pa0[r + 2]); pa0[r + 2] = p; r2 += p;                          \
      p = exp2f(pa0[r + 3]); pa0[r + 3] = p; r3 += p;                          \
      p = exp2f(pa1[r + 0]); pa1[r + 0] = p; r0 += p;                          \
      p = exp2f(pa1[r + 1]); pa1[r + 1] = p; r1 += p;                          \
      p = exp2f(pa1[r + 2]); pa1[r + 2] = p; r2 += p;                          \
      p = exp2f(pa1[r + 3]); pa1[r + 3] = p; r3 += p;                          \
    }                                                                          \
    l_run += (r0 + r1) + (r2 + r3);                                            \
    unsigned int c0[8], c1[8];                                                 \
    _Pragma("unroll") for (int u2 = 0; u2 < 8; ++u2) {                         \
      c0[u2] = cvtpk(pa0[2 * u2], pa0[2 * u2 + 1]);                            \
      c1[u2] = cvtpk(pa1[2 * u2], pa1[2 * u2 + 1]);                            \
    }                                                                          \
    pl32swap(c0[0], c0[2]); pl32swap(c0[1], c0[3]);                            \
    pl32swap(c0[4], c0[6]); pl32swap(c0[5], c0[7]);                            \
    pl32swap(c1[0], c1[2]); pl32swap(c1[1], c1[3]);                            \
    pl32swap(c1[4], c1[6]); pl32swap(c1[5], c1[7]);                            \
    __builtin_amdgcn_s_setprio(1);                                             \
    _Pragma("unroll") for (int ks = 0; ks < 4; ++ks) {                         \
      const int kb = ks >> 1, hf = (ks & 1) * 4;                               \
      const short8 pf = __builtin_bit_cast(                                    \
          short8, kb ? (uint4v){c1[hf], c1[hf + 1], c1[hf + 2], c1[hf + 3]}    \
                     : (uint4v){c0[hf], c0[hf + 1], c0[hf + 2], c0[hf + 3]});  \
      const short8 vf0 =                                                       \
          *reinterpret_cast<const short8*>(&Vl[BUF][off[0][ks]]);              \
      const short8 vf1 =                                                       \
          *reinterpret_cast<const short8*>(&Vl[BUF][off[1][ks]]);              \
      oa[0] = mfma32(vf0, pf, oa[0]);                                          \
      oa[1] = mfma32(vf1, pf, oa[1]);                                          \
    }                                                                          \
    __builtin_amdgcn_s_setprio(0);                                             \
  } while (0)

  STAGE(0);  // tile 0
  __syncthreads();
#pragma unroll 1
  for (int kt = 0; kt < 32; kt += 2) {
    STAGE(1);  // tile kt+1 in flight while computing kt
    TILE(0, kt);
    __syncthreads();
    if (kt + 2 < 32) STAGE(0);  // tile kt+2
    TILE(1, kt + 1);
    __syncthreads();
  }
#undef STAGE
#undef TILE

  // epilogue: combine lane-partial l across k-halves, normalize, repack, store
  l_run += __shfl_xor(l_run, 32);
  const float rinv = 1.f / l_run;
  unsigned int u[2][8];
#pragma unroll
  for (int vb = 0; vb < 2; ++vb) {
#pragma unroll
    for (int uu = 0; uu < 8; ++uu)
      u[vb][uu] = cvtpk(oa[vb][2 * uu] * rinv, oa[vb][2 * uu + 1] * rinv);
    pl32swap(u[vb][0], u[vb][2]);
    pl32swap(u[vb][1], u[vb][3]);
    pl32swap(u[vb][4], u[vb][6]);
    pl32swap(u[vb][5], u[vb][7]);
  }
  unsigned short* optr = O + (size_t)(b * SEQ + q0 + qi) * D_MODEL + h * 64;
#pragma unroll
  for (int cix = 0; cix < 4; ++cix) {
    const int vb = cix >> 1, hf = (cix & 1) * 4;
    *reinterpret_cast<short8*>(optr + cix * 16 + hi * 8) = __builtin_bit_cast(
        short8,
        (uint4v){u[vb][hf], u[vb][hf + 1], u[vb][hf + 2], u[vb][hf + 3]});
  }
}

// ---------------- launch ----------------
extern "C" void kernel_launch(void* const* d_in, const int* in_sizes, int n_in,
                              void* d_out, int out_size, void* d_ws, size_t ws_size,
                              hipStream_t stream) {
  const float* x  = (const float*)d_in[0];
  const int* mask = (const int*)d_in[1];
  const float* Wq = (const float*)d_in[2];
  const float* bq = (const float*)d_in[3];
  const float* Wk = (const float*)d_in[4];
  const float* bk = (const float*)d_in[5];
  const float* Wv = (const float*)d_in[6];
  const float* bv = (const float*)d_in[7];
  const float* Wo = (const float*)d_in[8];
  const float* bo = (const float*)d_in[9];

  char* ws = (char*)d_ws;
  const size_t SZ_X = (size_t)BATCH * SEQ * D_MODEL * 2;  // 16 MB
  unsigned short* xb    = (unsigned short*)(ws);                    // 16 MB @ 0
  unsigned short* Wqkvb = (unsigned short*)(ws + SZ_X);             // 6 MB @ 16M
  unsigned short* Wob   = (unsigned short*)(ws + SZ_X + 6u * 1024 * 1024);  // @ 22M
  unsigned short* QKVb  = (unsigned short*)(ws + 24u * 1024 * 1024);        // 48 MB
  unsigned short* VTb   = (unsigned short*)(ws + 72u * 1024 * 1024);        // 16 MB
  float*          bqkv  = (float*)(ws + 88u * 1024 * 1024);                 // 12 KB
  float*          maskb = (float*)(ws + 88u * 1024 * 1024 + 16384);         // 32 KB
  unsigned int*   flag2 = (unsigned int*)(ws + 88u * 1024 * 1024 + 49152);  // 16 B
  unsigned short* Ob    = xb;  // reuse: xb dead after QKV GEMM

  const int NX = BATCH * SEQ * D_MODEL;  // 8388608
  const int M = BATCH * SEQ;             // 8192

  cvt_f32_bf16<<<2048, 256, 0, stream>>>(x, xb, NX);
  cvt_w<<<dim3(512, 5), 256, 0, stream>>>(Wq, Wk, Wv, Wo, Wqkvb, Wob, mask, maskb);
  mask_flags<<<BATCH, 256, 0, stream>>>(mask, flag2, bq, bk, bv, bqkv);

  gemm_bt<1><<<dim3(3 * D_MODEL / 128, M / 128), 256, 0, stream>>>(
      xb, Wqkvb, bqkv, QKVb, VTb, M, 3 * D_MODEL, D_MODEL);

  attn_v6<<<BATCH * NHEAD * (SEQ / 256), 512, 0, stream>>>(QKVb, VTb, maskb,
                                                           flag2, Ob);

  gemm_bt<2><<<dim3(D_MODEL / 128, M / 128), 256, 0, stream>>>(
      Ob, Wob, bo, d_out, nullptr, M, D_MODEL, D_MODEL);
}

// Round 8
// 213.649 us; speedup vs baseline: 1.3608x; 1.1465x over previous
//
#include <hip/hip_runtime.h>
#include <stdint.h>

typedef __attribute__((ext_vector_type(8))) short short8;
typedef __attribute__((ext_vector_type(4))) float floatx4;
typedef __attribute__((ext_vector_type(16))) float f32x16;
typedef __attribute__((ext_vector_type(4))) unsigned int uint4v;

#define D_MODEL 1024
#define SEQ     2048
#define NHEAD   16
#define HDIM    64
#define BATCH   4
#define NW      (D_MODEL * D_MODEL)

__device__ __forceinline__ unsigned short f2b(float f) {
  unsigned int u = __builtin_bit_cast(unsigned int, f);
  u += 0x7FFFu + ((u >> 16) & 1u);
  return (unsigned short)(u >> 16);
}

__device__ __forceinline__ floatx4 mfma16(short8 a, short8 b, floatx4 c) {
  return __builtin_amdgcn_mfma_f32_16x16x32_bf16(a, b, c, 0, 0, 0);
}
__device__ __forceinline__ f32x16 mfma32(short8 a, short8 b, f32x16 c) {
  return __builtin_amdgcn_mfma_f32_32x32x16_bf16(a, b, c, 0, 0, 0);
}
__device__ __forceinline__ unsigned int cvtpk(float lo, float hi) {
  unsigned int r;
  asm("v_cvt_pk_bf16_f32 %0, %1, %2" : "=v"(r) : "v"(lo), "v"(hi));
  return r;
}
// v_permlane32_swap_b32 a, b: a's lanes 32-63 <-> b's lanes 0-31.
__device__ __forceinline__ void pl32swap(unsigned int &a, unsigned int &b) {
  asm("v_permlane32_swap_b32 %0, %1" : "+v"(a), "+v"(b));
}
// Raw v_exp_f32 (2^x). Args bounded: |x|<~50 fast path; -1e10 masked -> +0.
__device__ __forceinline__ float expfast(float x) {
  return __builtin_amdgcn_exp2f(x);
}

#define GLL16(gsrc, ldst)                                                     \
  __builtin_amdgcn_global_load_lds(                                           \
      (const __attribute__((address_space(1))) void*)(gsrc),                  \
      (__attribute__((address_space(3))) void*)(ldst), 16, 0, 0)

// ---------------- f32 -> bf16 conversion ----------------
__global__ void cvt_f32_bf16(const float* __restrict__ in,
                             unsigned short* __restrict__ out, int n) {
  int idx = (blockIdx.x * blockDim.x + threadIdx.x) * 4;
  int stride = gridDim.x * blockDim.x * 4;
  for (int i = idx; i < n; i += stride) {
    float4 v = *reinterpret_cast<const float4*>(in + i);
    ushort4 o;
    o.x = f2b(v.x); o.y = f2b(v.y); o.z = f2b(v.z); o.w = f2b(v.w);
    *reinterpret_cast<ushort4*>(out + i) = o;
  }
}

// Weights + mask prep: blockIdx.y 0..3 -> Wq,Wk,Wv (into Wqkv) / Wo; y==4 -> mask bias.
__global__ void cvt_w(const float* __restrict__ Wq, const float* __restrict__ Wk,
                      const float* __restrict__ Wv, const float* __restrict__ Wo,
                      unsigned short* __restrict__ Wqkv,
                      unsigned short* __restrict__ Wob,
                      const int* __restrict__ mask, float* __restrict__ maskb) {
  const int which = blockIdx.y;
  int idx = (blockIdx.x * blockDim.x + threadIdx.x) * 4;
  int stride = gridDim.x * blockDim.x * 4;
  if (which == 4) {
    for (int i = idx; i < BATCH * SEQ; i += stride) {
      int4 mv = *reinterpret_cast<const int4*>(mask + i);
      float4 o;
      o.x = mv.x ? 0.f : -1e10f;
      o.y = mv.y ? 0.f : -1e10f;
      o.z = mv.z ? 0.f : -1e10f;
      o.w = mv.w ? 0.f : -1e10f;
      *reinterpret_cast<float4*>(maskb + i) = o;
    }
    return;
  }
  const float* s = which == 0 ? Wq : which == 1 ? Wk : which == 2 ? Wv : Wo;
  unsigned short* d = which < 3 ? Wqkv + (size_t)which * NW : Wob;
  for (int i = idx; i < NW; i += stride) {
    float4 v = *reinterpret_cast<const float4*>(s + i);
    ushort4 o;
    o.x = f2b(v.x); o.y = f2b(v.y); o.z = f2b(v.z); o.w = f2b(v.w);
    *reinterpret_cast<ushort4*>(d + i) = o;
  }
}

// Per-(b, 64-key-chunk) "all keys valid" bitmask + bias concat (fused).
__global__ void mask_flags(const int* __restrict__ mask,
                           unsigned int* __restrict__ flags2,
                           const float* __restrict__ bq,
                           const float* __restrict__ bk,
                           const float* __restrict__ bv,
                           float* __restrict__ bqkv) {
  const int b = blockIdx.x, tid = threadIdx.x;
  if (tid < 64) {
    int ok = 0;
    if (tid < 32) {
      ok = 1;
      for (int i = 0; i < 64; ++i) ok &= mask[b * SEQ + tid * 64 + i];
    }
    unsigned long long bal = __ballot(ok);
    if (tid == 0) flags2[b] = (unsigned int)bal;
  }
  const int i = blockIdx.x * 256 + tid;  // 0..1023
  bqkv[i] = bq[i];
  bqkv[1024 + i] = bk[i];
  bqkv[2048 + i] = bv[i];
}

// ---------------- GEMM: C[m,n] = sum_k A[m,k]*B[n,k] + bias[n] ----------------
// 128x128 tile, BK=64 (m97 structure), 4 waves, each wave 64x64.
// T1 XCD-chunked bijective swizzle for L2 A-reuse.
// MODE 1: QKV fused — cols [0,1024) scaled by 0.125*log2e (Q pre-scale);
//   cols [2048,3072) -> transposed bf16 store into VT [b,h][d][s].
// MODE 2: f32 C.
template <int MODE>
__global__ __launch_bounds__(256) void gemm_bt(
    const unsigned short* __restrict__ A, const unsigned short* __restrict__ B,
    const float* __restrict__ bias, void* __restrict__ C,
    unsigned short* __restrict__ VT, int M, int N, int K) {
  __shared__ __align__(16) unsigned short As[128 * 64];
  __shared__ __align__(16) unsigned short Bs[128 * 64];
  const int tid = threadIdx.x;
  const int w = tid >> 6, l = tid & 63, lg = l >> 4, li = l & 15;
  const int GX = (MODE == 1) ? 24 : 8;      // N/128
  const int NWG = GX * 64;                   // M/128 = 64
  int id = blockIdx.y * GX + blockIdx.x;
  id = (id & 7) * (NWG >> 3) + (id >> 3);
  const int m0 = (id / GX) * 128, n0 = (id % GX) * 128;
  const int wr = w >> 1, wc = w & 1;

  floatx4 acc[4][4];
#pragma unroll
  for (int m = 0; m < 4; ++m)
#pragma unroll
    for (int n = 0; n < 4; ++n) acc[m][n] = (floatx4){0.f, 0.f, 0.f, 0.f};

  for (int k0 = 0; k0 < K; k0 += 64) {
    __syncthreads();
#pragma unroll
    for (int p = 0; p < 4; ++p) {
      const int c = p * 256 + tid;
      const int row = c >> 3;
      const int co = (c & 7) * 8;
      GLL16(A + (size_t)(m0 + row) * K + k0 + co, As + (p * 256 + w * 64) * 8);
      GLL16(B + (size_t)(n0 + row) * K + k0 + co, Bs + (p * 256 + w * 64) * 8);
    }
    __syncthreads();
#pragma unroll
    for (int kk = 0; kk < 2; ++kk) {
      short8 af[4], bfr[4];
#pragma unroll
      for (int m = 0; m < 4; ++m)
        af[m] = *reinterpret_cast<const short8*>(
            &As[(wr * 64 + m * 16 + li) * 64 + kk * 32 + lg * 8]);
#pragma unroll
      for (int n = 0; n < 4; ++n)
        bfr[n] = *reinterpret_cast<const short8*>(
            &Bs[(wc * 64 + n * 16 + li) * 64 + kk * 32 + lg * 8]);
#pragma unroll
      for (int m = 0; m < 4; ++m)
#pragma unroll
        for (int n = 0; n < 4; ++n) acc[m][n] = mfma16(af[m], bfr[n], acc[m][n]);
    }
  }

#pragma unroll
  for (int m = 0; m < 4; ++m)
#pragma unroll
    for (int n = 0; n < 4; ++n) {
      const int gcol = n0 + wc * 64 + n * 16 + li;
      const float bv = bias[gcol];
      const int grow0 = m0 + wr * 64 + m * 16 + lg * 4;
      if (MODE == 1 && n0 >= 2048) {
        const int vc = gcol - 2048;
        const int hh = vc >> 6, dd = vc & 63;
        const int b = grow0 >> 11, s0 = grow0 & 2047;
        ushort4 pk;
        pk.x = f2b(acc[m][n][0] + bv);
        pk.y = f2b(acc[m][n][1] + bv);
        pk.z = f2b(acc[m][n][2] + bv);
        pk.w = f2b(acc[m][n][3] + bv);
        *reinterpret_cast<ushort4*>(
            &VT[((size_t)((b * NHEAD + hh) * HDIM + dd)) * SEQ + s0]) = pk;
      } else {
        const float scl =
            (MODE == 1 && gcol < 1024) ? 0.18033688011112042f : 1.f;
#pragma unroll
        for (int r = 0; r < 4; ++r) {
          const float val = (acc[m][n][r] + bv) * scl;
          if (MODE == 2)
            reinterpret_cast<float*>(C)[(size_t)(grow0 + r) * N + gcol] = val;
          else
            reinterpret_cast<unsigned short*>(C)[(size_t)(grow0 + r) * N + gcol] =
                f2b(val);
        }
      }
    }
}

// ---------------- Flash attention v7: v6 + raw v_exp_f32 ----------------
// 8 waves x 32 q (QBLK=256), 2-buffer LDS, 1 barrier/tile. Only change vs v6:
// exp2f -> __builtin_amdgcn_exp2f (cuts ~6x VALU ops per exp; kernel is
// SIMD-issue-bound with VALU as dominant consumer).
__global__ __launch_bounds__(512) void attn_v7(
    const unsigned short* __restrict__ QKV, const unsigned short* __restrict__ VT,
    const float* __restrict__ maskb, const unsigned int* __restrict__ flags2,
    unsigned short* __restrict__ O) {
  __shared__ __align__(16) unsigned short Kl[2][64 * 64];
  __shared__ __align__(16) unsigned short Vl[2][64 * 64];
  const int tid = threadIdx.x, w = tid >> 6, l = tid & 63;
  const int qi = l & 31, hi = l >> 5;
  const int bid = blockIdx.x;
  const int qblk = bid >> 6, bh = bid & 63, b = bh >> 4, h = bh & 15;
  const int q0 = qblk * 256 + w * 32;

  // Q fragments (B-operand: lane qi = q-col, contraction d = ds*16 + hi*8 + j)
  const unsigned short* qptr = QKV + (size_t)(b * SEQ + q0 + qi) * 3072 + h * 64;
  short8 qf[4];
#pragma unroll
  for (int ds = 0; ds < 4; ++ds)
    qf[ds] = *reinterpret_cast<const short8*>(qptr + ds * 16 + hi * 8);

  // LDS read offsets (ushort units), shared by K and V reads: off[blk][sub]
  int off[2][4];
#pragma unroll
  for (int kb = 0; kb < 2; ++kb)
#pragma unroll
    for (int ds = 0; ds < 4; ++ds)
      off[kb][ds] = (kb * 32 + qi) * 64 + (((ds * 2 + hi) ^ (qi & 7)) * 8);

  // staging: 512 threads cover 64x64 tile: 1 chunk K + 1 chunk V per thread.
  const int srow = tid >> 3;
  const int swz = ((tid & 7) ^ (srow & 7)) * 8;
  const int ldst = w * 512;  // wave-uniform LDS base (ushort units)
  const unsigned short* kp0 =
      QKV + (size_t)(b * SEQ) * 3072 + D_MODEL + h * 64 + (size_t)srow * 3072 + swz;
  const unsigned short* vp0 =
      VT + (size_t)((b * NHEAD + h) * HDIM) * SEQ + (size_t)srow * SEQ + swz;

#define STAGE(BUF)                                                             \
  do {                                                                         \
    GLL16(kp0, &Kl[BUF][ldst]);                                                \
    GLL16(vp0, &Vl[BUF][ldst]);                                                \
    kp0 += 64 * 3072; vp0 += 64;                                               \
  } while (0)

  const float* mrow = maskb + b * SEQ;
  const unsigned int fl = flags2[b];
  f32x16 oa[2] = {};
  float l_run = 0.f;  // per-lane partial (own k-half); combined in epilogue

#define TILE(BUF, KT)                                                          \
  do {                                                                         \
    f32x16 pa0 = {}, pa1 = {};                                                 \
    __builtin_amdgcn_s_setprio(1);                                             \
    _Pragma("unroll") for (int ds = 0; ds < 4; ++ds) {                         \
      const short8 kf0 =                                                       \
          *reinterpret_cast<const short8*>(&Kl[BUF][off[0][ds]]);              \
      const short8 kf1 =                                                       \
          *reinterpret_cast<const short8*>(&Kl[BUF][off[1][ds]]);              \
      pa0 = mfma32(kf0, qf[ds], pa0);                                          \
      pa1 = mfma32(kf1, qf[ds], pa1);                                          \
    }                                                                          \
    __builtin_amdgcn_s_setprio(0);                                             \
    if (!((fl >> (KT)) & 1)) { /* slow path: some keys masked */               \
      _Pragma("unroll") for (int rq = 0; rq < 4; ++rq) {                       \
        const float4 m0 = *reinterpret_cast<const float4*>(                    \
            mrow + (KT) * 64 + rq * 8 + hi * 4);                               \
        const float4 m1 = *reinterpret_cast<const float4*>(                    \
            mrow + (KT) * 64 + 32 + rq * 8 + hi * 4);                          \
        pa0[rq * 4 + 0] += m0.x; pa0[rq * 4 + 1] += m0.y;                      \
        pa0[rq * 4 + 2] += m0.z; pa0[rq * 4 + 3] += m0.w;                      \
        pa1[rq * 4 + 0] += m1.x; pa1[rq * 4 + 1] += m1.y;                      \
        pa1[rq * 4 + 2] += m1.z; pa1[rq * 4 + 3] += m1.w;                      \
      }                                                                        \
    }                                                                          \
    float r0 = 0.f, r1 = 0.f, r2 = 0.f, r3 = 0.f;                              \
    _Pragma("unroll") for (int r = 0; r < 16; r += 4) {                        \
      float p;                                                                 \
      p = expfast(pa0[r + 0]); pa0[r + 0] = p; r0 += p;                        \
      p = expfast(pa0[r + 1]); pa0[r + 1] = p; r1 += p;                        \
      p = expfast(pa0[r + 2]); pa0[r + 2] = p; r2 += p;                        \
      p = expfast(pa0[r + 3]); pa0[r + 3] = p; r3 += p;                        \
      p = expfast(pa1[r + 0]); pa1[r + 0] = p; r0 += p;                        \
      p = expfast(pa1[r + 1]); pa1[r + 1] = p; r1 += p;                        \
      p = expfast(pa1[r + 2]); pa1[r + 2] = p; r2 += p;                        \
      p = expfast(pa1[r + 3]); pa1[r + 3] = p; r3 += p;                        \
    }                                                                          \
    l_run += (r0 + r1) + (r2 + r3);                                            \
    unsigned int c0[8], c1[8];                                                 \
    _Pragma("unroll") for (int u2 = 0; u2 < 8; ++u2) {                         \
      c0[u2] = cvtpk(pa0[2 * u2], pa0[2 * u2 + 1]);                            \
      c1[u2] = cvtpk(pa1[2 * u2], pa1[2 * u2 + 1]);                            \
    }                                                                          \
    pl32swap(c0[0], c0[2]); pl32swap(c0[1], c0[3]);                            \
    pl32swap(c0[4], c0[6]); pl32swap(c0[5], c0[7]);                            \
    pl32swap(c1[0], c1[2]); pl32swap(c1[1], c1[3]);                            \
    pl32swap(c1[4], c1[6]); pl32swap(c1[5], c1[7]);                            \
    __builtin_amdgcn_s_setprio(1);                                             \
    _Pragma("unroll") for (int ks = 0; ks < 4; ++ks) {                         \
      const int kb = ks >> 1, hf = (ks & 1) * 4;                               \
      const short8 pf = __builtin_bit_cast(                                    \
          short8, kb ? (uint4v){c1[hf], c1[hf + 1], c1[hf + 2], c1[hf + 3]}    \
                     : (uint4v){c0[hf], c0[hf + 1], c0[hf + 2], c0[hf + 3]});  \
      const short8 vf0 =                                                       \
          *reinterpret_cast<const short8*>(&Vl[BUF][off[0][ks]]);              \
      const short8 vf1 =                                                       \
          *reinterpret_cast<const short8*>(&Vl[BUF][off[1][ks]]);              \
      oa[0] = mfma32(vf0, pf, oa[0]);                                          \
      oa[1] = mfma32(vf1, pf, oa[1]);                                          \
    }                                                                          \
    __builtin_amdgcn_s_setprio(0);                                             \
  } while (0)

  STAGE(0);  // tile 0
  __syncthreads();
#pragma unroll 1
  for (int kt = 0; kt < 32; kt += 2) {
    STAGE(1);  // tile kt+1 in flight while computing kt
    TILE(0, kt);
    __syncthreads();
    if (kt + 2 < 32) STAGE(0);  // tile kt+2
    TILE(1, kt + 1);
    __syncthreads();
  }
#undef STAGE
#undef TILE

  // epilogue: combine lane-partial l across k-halves, normalize, repack, store
  l_run += __shfl_xor(l_run, 32);
  const float rinv = 1.f / l_run;
  unsigned int u[2][8];
#pragma unroll
  for (int vb = 0; vb < 2; ++vb) {
#pragma unroll
    for (int uu = 0; uu < 8; ++uu)
      u[vb][uu] = cvtpk(oa[vb][2 * uu] * rinv, oa[vb][2 * uu + 1] * rinv);
    pl32swap(u[vb][0], u[vb][2]);
    pl32swap(u[vb][1], u[vb][3]);
    pl32swap(u[vb][4], u[vb][6]);
    pl32swap(u[vb][5], u[vb][7]);
  }
  unsigned short* optr = O + (size_t)(b * SEQ + q0 + qi) * D_MODEL + h * 64;
#pragma unroll
  for (int cix = 0; cix < 4; ++cix) {
    const int vb = cix >> 1, hf = (cix & 1) * 4;
    *reinterpret_cast<short8*>(optr + cix * 16 + hi * 8) = __builtin_bit_cast(
        short8,
        (uint4v){u[vb][hf], u[vb][hf + 1], u[vb][hf + 2], u[vb][hf + 3]});
  }
}

// ---------------- launch ----------------
extern "C" void kernel_launch(void* const* d_in, const int* in_sizes, int n_in,
                              void* d_out, int out_size, void* d_ws, size_t ws_size,
                              hipStream_t stream) {
  const float* x  = (const float*)d_in[0];
  const int* mask = (const int*)d_in[1];
  const float* Wq = (const float*)d_in[2];
  const float* bq = (const float*)d_in[3];
  const float* Wk = (const float*)d_in[4];
  const float* bk = (const float*)d_in[5];
  const float* Wv = (const float*)d_in[6];
  const float* bv = (const float*)d_in[7];
  const float* Wo = (const float*)d_in[8];
  const float* bo = (const float*)d_in[9];

  char* ws = (char*)d_ws;
  const size_t SZ_X = (size_t)BATCH * SEQ * D_MODEL * 2;  // 16 MB
  unsigned short* xb    = (unsigned short*)(ws);                    // 16 MB @ 0
  unsigned short* Wqkvb = (unsigned short*)(ws + SZ_X);             // 6 MB @ 16M
  unsigned short* Wob   = (unsigned short*)(ws + SZ_X + 6u * 1024 * 1024);  // @ 22M
  unsigned short* QKVb  = (unsigned short*)(ws + 24u * 1024 * 1024);        // 48 MB
  unsigned short* VTb   = (unsigned short*)(ws + 72u * 1024 * 1024);        // 16 MB
  float*          bqkv  = (float*)(ws + 88u * 1024 * 1024);                 // 12 KB
  float*          maskb = (float*)(ws + 88u * 1024 * 1024 + 16384);         // 32 KB
  unsigned int*   flag2 = (unsigned int*)(ws + 88u * 1024 * 1024 + 49152);  // 16 B
  unsigned short* Ob    = xb;  // reuse: xb dead after QKV GEMM

  const int NX = BATCH * SEQ * D_MODEL;  // 8388608
  const int M = BATCH * SEQ;             // 8192

  cvt_f32_bf16<<<2048, 256, 0, stream>>>(x, xb, NX);
  cvt_w<<<dim3(512, 5), 256, 0, stream>>>(Wq, Wk, Wv, Wo, Wqkvb, Wob, mask, maskb);
  mask_flags<<<BATCH, 256, 0, stream>>>(mask, flag2, bq, bk, bv, bqkv);

  gemm_bt<1><<<dim3(3 * D_MODEL / 128, M / 128), 256, 0, stream>>>(
      xb, Wqkvb, bqkv, QKVb, VTb, M, 3 * D_MODEL, D_MODEL);

  attn_v7<<<BATCH * NHEAD * (SEQ / 256), 512, 0, stream>>>(QKVb, VTb, maskb,
                                                           flag2, Ob);

  gemm_bt<2><<<dim3(D_MODEL / 128, M / 128), 256, 0, stream>>>(
      Ob, Wob, bo, d_out, nullptr, M, D_MODEL, D_MODEL);
}

// Round 9
// 185.467 us; speedup vs baseline: 1.5675x; 1.1520x over previous
//
#include <hip/hip_runtime.h>
#include <stdint.h>

typedef __attribute__((ext_vector_type(8))) short short8;
typedef __attribute__((ext_vector_type(4))) float floatx4;
typedef __attribute__((ext_vector_type(16))) float f32x16;
typedef __attribute__((ext_vector_type(4))) unsigned int uint4v;

#define D_MODEL 1024
#define SEQ     2048
#define NHEAD   16
#define HDIM    64
#define BATCH   4
#define NW      (D_MODEL * D_MODEL)

__device__ __forceinline__ unsigned short f2b(float f) {
  unsigned int u = __builtin_bit_cast(unsigned int, f);
  u += 0x7FFFu + ((u >> 16) & 1u);
  return (unsigned short)(u >> 16);
}

__device__ __forceinline__ floatx4 mfma16(short8 a, short8 b, floatx4 c) {
  return __builtin_amdgcn_mfma_f32_16x16x32_bf16(a, b, c, 0, 0, 0);
}
__device__ __forceinline__ f32x16 mfma32(short8 a, short8 b, f32x16 c) {
  return __builtin_amdgcn_mfma_f32_32x32x16_bf16(a, b, c, 0, 0, 0);
}
__device__ __forceinline__ unsigned int cvtpk(float lo, float hi) {
  unsigned int r;
  asm("v_cvt_pk_bf16_f32 %0, %1, %2" : "=v"(r) : "v"(lo), "v"(hi));
  return r;
}
// v_permlane32_swap_b32 a, b: a's lanes 32-63 <-> b's lanes 0-31.
__device__ __forceinline__ void pl32swap(unsigned int &a, unsigned int &b) {
  asm("v_permlane32_swap_b32 %0, %1" : "+v"(a), "+v"(b));
}
// Raw v_exp_f32 (2^x). Args bounded: |x|<~50 fast path; -1e10 masked -> +0.
__device__ __forceinline__ float expfast(float x) {
  return __builtin_amdgcn_exp2f(x);
}

#define GLL16(gsrc, ldst)                                                     \
  __builtin_amdgcn_global_load_lds(                                           \
      (const __attribute__((address_space(1))) void*)(gsrc),                  \
      (__attribute__((address_space(3))) void*)(ldst), 16, 0, 0)

// ---------------- f32 -> bf16 conversion ----------------
__global__ void cvt_f32_bf16(const float* __restrict__ in,
                             unsigned short* __restrict__ out, int n) {
  int idx = (blockIdx.x * blockDim.x + threadIdx.x) * 4;
  int stride = gridDim.x * blockDim.x * 4;
  for (int i = idx; i < n; i += stride) {
    float4 v = *reinterpret_cast<const float4*>(in + i);
    ushort4 o;
    o.x = f2b(v.x); o.y = f2b(v.y); o.z = f2b(v.z); o.w = f2b(v.w);
    *reinterpret_cast<ushort4*>(out + i) = o;
  }
}

// Weights + mask prep: blockIdx.y 0..3 -> Wq,Wk,Wv (into Wqkv) / Wo; y==4 -> mask bias.
__global__ void cvt_w(const float* __restrict__ Wq, const float* __restrict__ Wk,
                      const float* __restrict__ Wv, const float* __restrict__ Wo,
                      unsigned short* __restrict__ Wqkv,
                      unsigned short* __restrict__ Wob,
                      const int* __restrict__ mask, float* __restrict__ maskb) {
  const int which = blockIdx.y;
  int idx = (blockIdx.x * blockDim.x + threadIdx.x) * 4;
  int stride = gridDim.x * blockDim.x * 4;
  if (which == 4) {
    for (int i = idx; i < BATCH * SEQ; i += stride) {
      int4 mv = *reinterpret_cast<const int4*>(mask + i);
      float4 o;
      o.x = mv.x ? 0.f : -1e10f;
      o.y = mv.y ? 0.f : -1e10f;
      o.z = mv.z ? 0.f : -1e10f;
      o.w = mv.w ? 0.f : -1e10f;
      *reinterpret_cast<float4*>(maskb + i) = o;
    }
    return;
  }
  const float* s = which == 0 ? Wq : which == 1 ? Wk : which == 2 ? Wv : Wo;
  unsigned short* d = which < 3 ? Wqkv + (size_t)which * NW : Wob;
  for (int i = idx; i < NW; i += stride) {
    float4 v = *reinterpret_cast<const float4*>(s + i);
    ushort4 o;
    o.x = f2b(v.x); o.y = f2b(v.y); o.z = f2b(v.z); o.w = f2b(v.w);
    *reinterpret_cast<ushort4*>(d + i) = o;
  }
}

// Per-(b, 64-key-chunk) "all keys valid" bitmask + bias concat (fused).
__global__ void mask_flags(const int* __restrict__ mask,
                           unsigned int* __restrict__ flags2,
                           const float* __restrict__ bq,
                           const float* __restrict__ bk,
                           const float* __restrict__ bv,
                           float* __restrict__ bqkv) {
  const int b = blockIdx.x, tid = threadIdx.x;
  if (tid < 64) {
    int ok = 0;
    if (tid < 32) {
      ok = 1;
      for (int i = 0; i < 64; ++i) ok &= mask[b * SEQ + tid * 64 + i];
    }
    unsigned long long bal = __ballot(ok);
    if (tid == 0) flags2[b] = (unsigned int)bal;
  }
  const int i = blockIdx.x * 256 + tid;  // 0..1023
  bqkv[i] = bq[i];
  bqkv[1024 + i] = bk[i];
  bqkv[2048 + i] = bv[i];
}

// ---------------- GEMM v2: double-buffered 2-phase + T2 swizzle ----------------
// C[m,n] = sum_k A[m,k]*B[n,k] + bias[n]. 128x128 tile, BK=64, 4 waves.
// 2-phase: STAGE(next tile) issued BEFORE compute(current); 1 barrier/tile.
// T2: LDS col-slot XOR row&7 (pre-swizzled global source, swizzled read).
// T1 XCD-chunked bijective swizzle for L2 A-reuse.
// MODE 1: QKV fused — cols [0,1024) scaled by 0.125*log2e (Q pre-scale);
//   cols [2048,3072) -> transposed bf16 store into VT [b,h][d][s].
// MODE 2: f32 C.
template <int MODE>
__global__ __launch_bounds__(256) void gemm_bt(
    const unsigned short* __restrict__ A, const unsigned short* __restrict__ B,
    const float* __restrict__ bias, void* __restrict__ C,
    unsigned short* __restrict__ VT, int M, int N, int K) {
  __shared__ __align__(16) unsigned short As[2][128 * 64];
  __shared__ __align__(16) unsigned short Bs[2][128 * 64];
  const int tid = threadIdx.x;
  const int w = tid >> 6, l = tid & 63, lg = l >> 4, li = l & 15;
  const int GX = (MODE == 1) ? 24 : 8;      // N/128
  const int NWG = GX * 64;                   // M/128 = 64
  int id = blockIdx.y * GX + blockIdx.x;
  id = (id & 7) * (NWG >> 3) + (id >> 3);
  const int m0 = (id / GX) * 128, n0 = (id % GX) * 128;
  const int wr = w >> 1, wc = w & 1;

  floatx4 acc[4][4];
#pragma unroll
  for (int m = 0; m < 4; ++m)
#pragma unroll
    for (int n = 0; n < 4; ++n) acc[m][n] = (floatx4){0.f, 0.f, 0.f, 0.f};

  // stage: chunk c=p*256+tid -> row=c>>3, slot=c&7; source col pre-swizzled
  // slot^(row&7) so linear LDS + XOR'd read = conflict-free (rule 21).
#define GSTAGE(BUF, T)                                                         \
  do {                                                                         \
    _Pragma("unroll") for (int p = 0; p < 4; ++p) {                            \
      const int c = p * 256 + tid;                                             \
      const int row = c >> 3;                                                  \
      const int co = ((c & 7) ^ (row & 7)) * 8;                                \
      GLL16(A + (size_t)(m0 + row) * K + (T) * 64 + co,                        \
            &As[BUF][(p * 256 + w * 64) * 8]);                                 \
      GLL16(B + (size_t)(n0 + row) * K + (T) * 64 + co,                        \
            &Bs[BUF][(p * 256 + w * 64) * 8]);                                 \
    }                                                                          \
  } while (0)

#define GCOMP(BUF)                                                             \
  do {                                                                         \
    _Pragma("unroll") for (int kk = 0; kk < 2; ++kk) {                         \
      short8 af[4], bfr[4];                                                    \
      _Pragma("unroll") for (int m = 0; m < 4; ++m)                            \
        af[m] = *reinterpret_cast<const short8*>(                              \
            &As[BUF][(wr * 64 + m * 16 + li) * 64 +                            \
                     (((kk * 4 + lg) ^ (li & 7)) * 8)]);                       \
      _Pragma("unroll") for (int n = 0; n < 4; ++n)                            \
        bfr[n] = *reinterpret_cast<const short8*>(                             \
            &Bs[BUF][(wc * 64 + n * 16 + li) * 64 +                            \
                     (((kk * 4 + lg) ^ (li & 7)) * 8)]);                       \
      __builtin_amdgcn_s_setprio(1);                                           \
      _Pragma("unroll") for (int m = 0; m < 4; ++m)                            \
        _Pragma("unroll") for (int n = 0; n < 4; ++n)                          \
            acc[m][n] = mfma16(af[m], bfr[n], acc[m][n]);                      \
      __builtin_amdgcn_s_setprio(0);                                           \
    }                                                                          \
  } while (0)

  const int NT = K >> 6;  // 16 for K=1024
  GSTAGE(0, 0);
  __syncthreads();
#pragma unroll 1
  for (int t = 0; t < NT; t += 2) {
    if (t + 1 < NT) GSTAGE(1, t + 1);  // next tile in flight under compute
    GCOMP(0);
    __syncthreads();
    if (t + 2 < NT) GSTAGE(0, t + 2);
    GCOMP(1);
    __syncthreads();
  }
#undef GSTAGE
#undef GCOMP

#pragma unroll
  for (int m = 0; m < 4; ++m)
#pragma unroll
    for (int n = 0; n < 4; ++n) {
      const int gcol = n0 + wc * 64 + n * 16 + li;
      const float bv = bias[gcol];
      const int grow0 = m0 + wr * 64 + m * 16 + lg * 4;
      if (MODE == 1 && n0 >= 2048) {
        const int vc = gcol - 2048;
        const int hh = vc >> 6, dd = vc & 63;
        const int b = grow0 >> 11, s0 = grow0 & 2047;
        ushort4 pk;
        pk.x = f2b(acc[m][n][0] + bv);
        pk.y = f2b(acc[m][n][1] + bv);
        pk.z = f2b(acc[m][n][2] + bv);
        pk.w = f2b(acc[m][n][3] + bv);
        *reinterpret_cast<ushort4*>(
            &VT[((size_t)((b * NHEAD + hh) * HDIM + dd)) * SEQ + s0]) = pk;
      } else {
        const float scl =
            (MODE == 1 && gcol < 1024) ? 0.18033688011112042f : 1.f;
#pragma unroll
        for (int r = 0; r < 4; ++r) {
          const float val = (acc[m][n][r] + bv) * scl;
          if (MODE == 2)
            reinterpret_cast<float*>(C)[(size_t)(grow0 + r) * N + gcol] = val;
          else
            reinterpret_cast<unsigned short*>(C)[(size_t)(grow0 + r) * N + gcol] =
                f2b(val);
        }
      }
    }
}

// ---------------- Flash attention v7 (frozen from round 8) ----------------
__global__ __launch_bounds__(512) void attn_v7(
    const unsigned short* __restrict__ QKV, const unsigned short* __restrict__ VT,
    const float* __restrict__ maskb, const unsigned int* __restrict__ flags2,
    unsigned short* __restrict__ O) {
  __shared__ __align__(16) unsigned short Kl[2][64 * 64];
  __shared__ __align__(16) unsigned short Vl[2][64 * 64];
  const int tid = threadIdx.x, w = tid >> 6, l = tid & 63;
  const int qi = l & 31, hi = l >> 5;
  const int bid = blockIdx.x;
  const int qblk = bid >> 6, bh = bid & 63, b = bh >> 4, h = bh & 15;
  const int q0 = qblk * 256 + w * 32;

  const unsigned short* qptr = QKV + (size_t)(b * SEQ + q0 + qi) * 3072 + h * 64;
  short8 qf[4];
#pragma unroll
  for (int ds = 0; ds < 4; ++ds)
    qf[ds] = *reinterpret_cast<const short8*>(qptr + ds * 16 + hi * 8);

  int off[2][4];
#pragma unroll
  for (int kb = 0; kb < 2; ++kb)
#pragma unroll
    for (int ds = 0; ds < 4; ++ds)
      off[kb][ds] = (kb * 32 + qi) * 64 + (((ds * 2 + hi) ^ (qi & 7)) * 8);

  const int srow = tid >> 3;
  const int swz = ((tid & 7) ^ (srow & 7)) * 8;
  const int ldst = w * 512;  // wave-uniform LDS base (ushort units)
  const unsigned short* kp0 =
      QKV + (size_t)(b * SEQ) * 3072 + D_MODEL + h * 64 + (size_t)srow * 3072 + swz;
  const unsigned short* vp0 =
      VT + (size_t)((b * NHEAD + h) * HDIM) * SEQ + (size_t)srow * SEQ + swz;

#define STAGE(BUF)                                                             \
  do {                                                                         \
    GLL16(kp0, &Kl[BUF][ldst]);                                                \
    GLL16(vp0, &Vl[BUF][ldst]);                                                \
    kp0 += 64 * 3072; vp0 += 64;                                               \
  } while (0)

  const float* mrow = maskb + b * SEQ;
  const unsigned int fl = flags2[b];
  f32x16 oa[2] = {};
  float l_run = 0.f;  // per-lane partial (own k-half); combined in epilogue

#define TILE(BUF, KT)                                                          \
  do {                                                                         \
    f32x16 pa0 = {}, pa1 = {};                                                 \
    __builtin_amdgcn_s_setprio(1);                                             \
    _Pragma("unroll") for (int ds = 0; ds < 4; ++ds) {                         \
      const short8 kf0 =                                                       \
          *reinterpret_cast<const short8*>(&Kl[BUF][off[0][ds]]);              \
      const short8 kf1 =                                                       \
          *reinterpret_cast<const short8*>(&Kl[BUF][off[1][ds]]);              \
      pa0 = mfma32(kf0, qf[ds], pa0);                                          \
      pa1 = mfma32(kf1, qf[ds], pa1);                                          \
    }                                                                          \
    __builtin_amdgcn_s_setprio(0);                                             \
    if (!((fl >> (KT)) & 1)) { /* slow path: some keys masked */               \
      _Pragma("unroll") for (int rq = 0; rq < 4; ++rq) {                       \
        const float4 m0 = *reinterpret_cast<const float4*>(                    \
            mrow + (KT) * 64 + rq * 8 + hi * 4);                               \
        const float4 m1 = *reinterpret_cast<const float4*>(                    \
            mrow + (KT) * 64 + 32 + rq * 8 + hi * 4);                          \
        pa0[rq * 4 + 0] += m0.x; pa0[rq * 4 + 1] += m0.y;                      \
        pa0[rq * 4 + 2] += m0.z; pa0[rq * 4 + 3] += m0.w;                      \
        pa1[rq * 4 + 0] += m1.x; pa1[rq * 4 + 1] += m1.y;                      \
        pa1[rq * 4 + 2] += m1.z; pa1[rq * 4 + 3] += m1.w;                      \
      }                                                                        \
    }                                                                          \
    float r0 = 0.f, r1 = 0.f, r2 = 0.f, r3 = 0.f;                              \
    _Pragma("unroll") for (int r = 0; r < 16; r += 4) {                        \
      float p;                                                                 \
      p = expfast(pa0[r + 0]); pa0[r + 0] = p; r0 += p;                        \
      p = expfast(pa0[r + 1]); pa0[r + 1] = p; r1 += p;                        \
      p = expfast(pa0[r + 2]); pa0[r + 2] = p; r2 += p;                        \
      p = expfast(pa0[r + 3]); pa0[r + 3] = p; r3 += p;                        \
      p = expfast(pa1[r + 0]); pa1[r + 0] = p; r0 += p;                        \
      p = expfast(pa1[r + 1]); pa1[r + 1] = p; r1 += p;                        \
      p = expfast(pa1[r + 2]); pa1[r + 2] = p; r2 += p;                        \
      p = expfast(pa1[r + 3]); pa1[r + 3] = p; r3 += p;                        \
    }                                                                          \
    l_run += (r0 + r1) + (r2 + r3);                                            \
    unsigned int c0[8], c1[8];                                                 \
    _Pragma("unroll") for (int u2 = 0; u2 < 8; ++u2) {                         \
      c0[u2] = cvtpk(pa0[2 * u2], pa0[2 * u2 + 1]);                            \
      c1[u2] = cvtpk(pa1[2 * u2], pa1[2 * u2 + 1]);                            \
    }                                                                          \
    pl32swap(c0[0], c0[2]); pl32swap(c0[1], c0[3]);                            \
    pl32swap(c0[4], c0[6]); pl32swap(c0[5], c0[7]);                            \
    pl32swap(c1[0], c1[2]); pl32swap(c1[1], c1[3]);                            \
    pl32swap(c1[4], c1[6]); pl32swap(c1[5], c1[7]);                            \
    __builtin_amdgcn_s_setprio(1);                                             \
    _Pragma("unroll") for (int ks = 0; ks < 4; ++ks) {                         \
      const int kb = ks >> 1, hf = (ks & 1) * 4;                               \
      const short8 pf = __builtin_bit_cast(                                    \
          short8, kb ? (uint4v){c1[hf], c1[hf + 1], c1[hf + 2], c1[hf + 3]}    \
                     : (uint4v){c0[hf], c0[hf + 1], c0[hf + 2], c0[hf + 3]});  \
      const short8 vf0 =                                                       \
          *reinterpret_cast<const short8*>(&Vl[BUF][off[0][ks]]);              \
      const short8 vf1 =                                                       \
          *reinterpret_cast<const short8*>(&Vl[BUF][off[1][ks]]);              \
      oa[0] = mfma32(vf0, pf, oa[0]);                                          \
      oa[1] = mfma32(vf1, pf, oa[1]);                                          \
    }                                                                          \
    __builtin_amdgcn_s_setprio(0);                                             \
  } while (0)

  STAGE(0);  // tile 0
  __syncthreads();
#pragma unroll 1
  for (int kt = 0; kt < 32; kt += 2) {
    STAGE(1);  // tile kt+1 in flight while computing kt
    TILE(0, kt);
    __syncthreads();
    if (kt + 2 < 32) STAGE(0);  // tile kt+2
    TILE(1, kt + 1);
    __syncthreads();
  }
#undef STAGE
#undef TILE

  // epilogue: combine lane-partial l across k-halves, normalize, repack, store
  l_run += __shfl_xor(l_run, 32);
  const float rinv = 1.f / l_run;
  unsigned int u[2][8];
#pragma unroll
  for (int vb = 0; vb < 2; ++vb) {
#pragma unroll
    for (int uu = 0; uu < 8; ++uu)
      u[vb][uu] = cvtpk(oa[vb][2 * uu] * rinv, oa[vb][2 * uu + 1] * rinv);
    pl32swap(u[vb][0], u[vb][2]);
    pl32swap(u[vb][1], u[vb][3]);
    pl32swap(u[vb][4], u[vb][6]);
    pl32swap(u[vb][5], u[vb][7]);
  }
  unsigned short* optr = O + (size_t)(b * SEQ + q0 + qi) * D_MODEL + h * 64;
#pragma unroll
  for (int cix = 0; cix < 4; ++cix) {
    const int vb = cix >> 1, hf = (cix & 1) * 4;
    *reinterpret_cast<short8*>(optr + cix * 16 + hi * 8) = __builtin_bit_cast(
        short8,
        (uint4v){u[vb][hf], u[vb][hf + 1], u[vb][hf + 2], u[vb][hf + 3]});
  }
}

// ---------------- launch ----------------
extern "C" void kernel_launch(void* const* d_in, const int* in_sizes, int n_in,
                              void* d_out, int out_size, void* d_ws, size_t ws_size,
                              hipStream_t stream) {
  const float* x  = (const float*)d_in[0];
  const int* mask = (const int*)d_in[1];
  const float* Wq = (const float*)d_in[2];
  const float* bq = (const float*)d_in[3];
  const float* Wk = (const float*)d_in[4];
  const float* bk = (const float*)d_in[5];
  const float* Wv = (const float*)d_in[6];
  const float* bv = (const float*)d_in[7];
  const float* Wo = (const float*)d_in[8];
  const float* bo = (const float*)d_in[9];

  char* ws = (char*)d_ws;
  const size_t SZ_X = (size_t)BATCH * SEQ * D_MODEL * 2;  // 16 MB
  unsigned short* xb    = (unsigned short*)(ws);                    // 16 MB @ 0
  unsigned short* Wqkvb = (unsigned short*)(ws + SZ_X);             // 6 MB @ 16M
  unsigned short* Wob   = (unsigned short*)(ws + SZ_X + 6u * 1024 * 1024);  // @ 22M
  unsigned short* QKVb  = (unsigned short*)(ws + 24u * 1024 * 1024);        // 48 MB
  unsigned short* VTb   = (unsigned short*)(ws + 72u * 1024 * 1024);        // 16 MB
  float*          bqkv  = (float*)(ws + 88u * 1024 * 1024);                 // 12 KB
  float*          maskb = (float*)(ws + 88u * 1024 * 1024 + 16384);         // 32 KB
  unsigned int*   flag2 = (unsigned int*)(ws + 88u * 1024 * 1024 + 49152);  // 16 B
  unsigned short* Ob    = xb;  // reuse: xb dead after QKV GEMM

  const int NX = BATCH * SEQ * D_MODEL;  // 8388608
  const int M = BATCH * SEQ;             // 8192

  cvt_f32_bf16<<<2048, 256, 0, stream>>>(x, xb, NX);
  cvt_w<<<dim3(512, 5), 256, 0, stream>>>(Wq, Wk, Wv, Wo, Wqkvb, Wob, mask, maskb);
  mask_flags<<<BATCH, 256, 0, stream>>>(mask, flag2, bq, bk, bv, bqkv);

  gemm_bt<1><<<dim3(3 * D_MODEL / 128, M / 128), 256, 0, stream>>>(
      xb, Wqkvb, bqkv, QKVb, VTb, M, 3 * D_MODEL, D_MODEL);

  attn_v7<<<BATCH * NHEAD * (SEQ / 256), 512, 0, stream>>>(QKVb, VTb, maskb,
                                                           flag2, Ob);

  gemm_bt<2><<<dim3(D_MODEL / 128, M / 128), 256, 0, stream>>>(
      Ob, Wob, bo, d_out, nullptr, M, D_MODEL, D_MODEL);
}